// Round 1
// 1151.473 us; speedup vs baseline: 1.0212x; 1.0212x over previous
//
#include <hip/hip_runtime.h>
#include <hip/hip_bf16.h>

#define FDIM 256
#define FOUT 40

typedef __attribute__((ext_vector_type(8))) short short8;
typedef __attribute__((ext_vector_type(4))) float floatx4;

__device__ __forceinline__ float bf2f(unsigned short u) {
  unsigned int x = ((unsigned int)u) << 16;
  float f;
  __builtin_memcpy(&f, &x, 4);
  return f;
}
__device__ __forceinline__ unsigned short f2bf(float f) {
  __hip_bfloat16 h = __float2bfloat16(f);
  unsigned short u;
  __builtin_memcpy(&u, &h, 2);
  return u;
}

// ---------------- edge_index layout detection + normalization ----------------

__global__ void detect_k(const int* __restrict__ raw, int nwords, int* __restrict__ flag) {
  if (threadIdx.x == 0) *flag = 0;
  __syncthreads();
  int found = 0;
  for (int w = 1 + 2 * threadIdx.x; w < nwords; w += 512)
    if (raw[w] != 0) { found = 1; break; }
  if (found) atomicOr(flag, 1);  // 1 => int32 layout
}

__global__ void normalize_k(const int* __restrict__ raw, const int* __restrict__ flag,
                            int* __restrict__ srcN, int* __restrict__ dstN, int e) {
  int i = blockIdx.x * 256 + threadIdx.x;
  if (i >= e) return;
  if (*flag) {
    srcN[i] = raw[i];
    dstN[i] = raw[e + i];
  } else {
    srcN[i] = raw[2 * i];
    dstN[i] = raw[2 * (e + i)];
  }
}

// ---------------- CSR build ----------------

__global__ void zero_cnt_k(int* cnt, int n) {
  int i = blockIdx.x * 256 + threadIdx.x;
  if (i < n) cnt[i] = 0;
}

__global__ void count_k(const int* __restrict__ dst, int* __restrict__ cnt, int e, int n) {
  int i = blockIdx.x * 256 + threadIdx.x;
  if (i < e) {
    int d = dst[i];
    if (d >= 0 && d < n) atomicAdd(&cnt[d], 1);
  }
}

__global__ void dis_k(const int* __restrict__ cnt, float* __restrict__ dis, int n) {
  int i = blockIdx.x * 256 + threadIdx.x;
  if (i < n) dis[i] = rsqrtf((float)cnt[i] + 1.0f);
}

__global__ void scan_a_k(const int* __restrict__ cnt, int* __restrict__ excl,
                         int* __restrict__ bsum, int n) {
  __shared__ int sh[1024];
  int t = threadIdx.x;
  int gid = blockIdx.x * 1024 + t;
  int v = (gid < n) ? cnt[gid] : 0;
  sh[t] = v;
  __syncthreads();
  for (int off = 1; off < 1024; off <<= 1) {
    int x = (t >= off) ? sh[t - off] : 0;
    __syncthreads();
    sh[t] += x;
    __syncthreads();
  }
  if (gid < n) excl[gid] = sh[t] - v;
  if (t == 1023) bsum[blockIdx.x] = sh[1023];
}

__global__ void scan_b_k(int* __restrict__ bsum, int nb) {
  __shared__ int sh[1024];
  int t = threadIdx.x;
  int v = (t < nb) ? bsum[t] : 0;
  sh[t] = v;
  __syncthreads();
  for (int off = 1; off < 1024; off <<= 1) {
    int x = (t >= off) ? sh[t - off] : 0;
    __syncthreads();
    sh[t] += x;
    __syncthreads();
  }
  if (t < nb) bsum[t] = sh[t] - v;
}

__global__ void scan_c_k(int* __restrict__ row_ptr, const int* __restrict__ bsum,
                         const int* __restrict__ cnt, int* __restrict__ cursor, int n) {
  int gid = blockIdx.x * 1024 + threadIdx.x;
  if (gid < n) {
    int r = row_ptr[gid] + bsum[blockIdx.x];
    row_ptr[gid] = r;
    cursor[gid] = r;
    if (gid == n - 1) row_ptr[n] = r + cnt[gid];
  }
}

__global__ void fill_k(const int* __restrict__ src, const int* __restrict__ dst,
                       int* __restrict__ cursor, int* __restrict__ col, int e, int n) {
  int i = blockIdx.x * 256 + threadIdx.x;
  if (i < e) {
    int d = dst[i];
    if (d >= 0 && d < n) {
      int slot = atomicAdd(&cursor[d], 1);
      int s = src[i];
      s = min(max(s, 0), n - 1);
      col[slot] = s;
    }
  }
}

// ---------------- W1T: bf16 transpose of fp32 W1 ----------------

__global__ void transp_k(const float* __restrict__ in, unsigned short* __restrict__ out) {
  out[(size_t)blockIdx.x * FDIM + threadIdx.x] =
      f2bf(in[(size_t)threadIdx.x * FDIM + blockIdx.x]);
}

// ---------------- Wc = W2 @ Wlin (fp32); bc = b2 @ Wlin + blin ----------------

__global__ __launch_bounds__(64) void wc_k(const float* __restrict__ W2,
                                           const float* __restrict__ Wlin,
                                           float* __restrict__ Wc) {
  __shared__ float row[FDIM];
  int k = blockIdx.x, t = threadIdx.x;
  for (int j = t; j < FDIM; j += 64) row[j] = W2[(size_t)k * FDIM + j];
  __syncthreads();
  if (t < FOUT) {
    float acc = 0.f;
    for (int j = 0; j < FDIM; ++j) acc += row[j] * Wlin[(size_t)j * FOUT + t];
    Wc[(size_t)k * FOUT + t] = acc;
  }
}

__global__ __launch_bounds__(64) void bc_k(const float* __restrict__ b2,
                                           const float* __restrict__ Wlin,
                                           const float* __restrict__ blin,
                                           float* __restrict__ bc) {
  int t = threadIdx.x;
  if (t < FOUT) {
    float acc = blin[t];
    for (int j = 0; j < FDIM; ++j) acc += b2[j] * Wlin[(size_t)j * FOUT + t];
    bc[t] = acc;
  }
}

// ---------------- xs = bf16(x * dis[row]) ----------------

__global__ __launch_bounds__(256) void fold_k(const float* __restrict__ x,
                                              const float* __restrict__ dis,
                                              unsigned short* __restrict__ xs, int n) {
  int total = n * (FDIM / 4);
  for (int idx = blockIdx.x * 256 + threadIdx.x; idx < total; idx += gridDim.x * 256) {
    int row = idx >> 6;
    float di = dis[row];
    float4 v = *(const float4*)(x + (size_t)idx * 4);
    ushort4 o;
    o.x = f2bf(v.x * di); o.y = f2bf(v.y * di); o.z = f2bf(v.z * di); o.w = f2bf(v.w * di);
    *(ushort4*)(xs + (size_t)idx * 4) = o;
  }
}

// ---------------- agg over bf16 pre-folded table: out = bf16( dis_i * (tab[i] + sum tab[src]) ) ----------------
// readlane broadcast -> SGPR row base (saddr loads, no ds_bpermute, SALU addr math);
// full 8-edge batches use plain adds, only the tail batch is weight-predicated.

__global__ __launch_bounds__(256) void agg_b_k(
    const unsigned short* __restrict__ tab, const int* __restrict__ row_ptr,
    const int* __restrict__ col, const float* __restrict__ dis,
    unsigned short* __restrict__ out, int n) {
  int wave = threadIdx.x >> 6, lane = threadIdx.x & 63;
  int wid = blockIdx.x * 4 + wave;
  int nw = gridDim.x * 4;
  int f = lane * 4;
  for (int i = wid; i < n; i += nw) {
    ushort4 v = *(const ushort4*)(tab + (size_t)i * FDIM + f);
    float a0 = bf2f(v.x), a1 = bf2f(v.y), a2 = bf2f(v.z), a3 = bf2f(v.w);
    int beg = row_ptr[i], end = row_ptr[i + 1];
    for (int j0 = beg; j0 < end; j0 += 64) {
      int jj = j0 + lane;
      int cs = (jj < end) ? col[jj] : 0;
      int cc = min(64, end - j0);
      int kf = cc & ~7;
      for (int k = 0; k < kf; k += 8) {
        int sl[8];
#pragma unroll
        for (int u = 0; u < 8; ++u) sl[u] = __builtin_amdgcn_readlane(cs, k + u);
        ushort4 g[8];
#pragma unroll
        for (int u = 0; u < 8; ++u)
          g[u] = *(const ushort4*)(tab + (size_t)sl[u] * FDIM + f);
#pragma unroll
        for (int u = 0; u < 8; ++u) {
          a0 += bf2f(g[u].x); a1 += bf2f(g[u].y);
          a2 += bf2f(g[u].z); a3 += bf2f(g[u].w);
        }
      }
      if (kf < cc) {
        int sl[8]; float w[8];
#pragma unroll
        for (int u = 0; u < 8; ++u) {
          int ku = kf + u;
          sl[u] = __builtin_amdgcn_readlane(cs, ku & 63);
          w[u] = (ku < cc) ? 1.f : 0.f;
        }
        ushort4 g[8];
#pragma unroll
        for (int u = 0; u < 8; ++u)
          g[u] = *(const ushort4*)(tab + (size_t)sl[u] * FDIM + f);
#pragma unroll
        for (int u = 0; u < 8; ++u) {
          a0 = fmaf(w[u], bf2f(g[u].x), a0);
          a1 = fmaf(w[u], bf2f(g[u].y), a1);
          a2 = fmaf(w[u], bf2f(g[u].z), a2);
          a3 = fmaf(w[u], bf2f(g[u].w), a3);
        }
      }
    }
    float di = dis[i];
    ushort4 o;
    o.x = f2bf(a0 * di); o.y = f2bf(a1 * di); o.z = f2bf(a2 * di); o.w = f2bf(a3 * di);
    *(ushort4*)(out + (size_t)i * FDIM + f) = o;
  }
}

// ---------------- fallback: agg over fp32 x with per-edge dis weight (unchanged, dead in big path) ----------------

__global__ __launch_bounds__(256) void agg_f_k(
    const float* __restrict__ x, const int* __restrict__ row_ptr,
    const int* __restrict__ col, const float* __restrict__ dis,
    unsigned short* __restrict__ out, int n) {
  int wave = threadIdx.x >> 6, lane = threadIdx.x & 63;
  int wid = blockIdx.x * 4 + wave;
  int nw = gridDim.x * 4;
  for (int i = wid; i < n; i += nw) {
    int f = lane * 4;
    float di = dis[i];
    float4 v = *(const float4*)(x + (size_t)i * FDIM + f);
    float a0 = v.x * di, a1 = v.y * di, a2 = v.z * di, a3 = v.w * di;
    int beg = row_ptr[i], end = row_ptr[i + 1];
    for (int j0 = beg; j0 < end; j0 += 64) {
      int jj = j0 + lane;
      int cs = (jj < end) ? col[jj] : 0;
      float cd = (jj < end) ? dis[cs] : 0.f;
      int cc = min(64, end - j0);
      for (int k = 0; k < cc; k += 8) {
        float4 g[8];
        float w[8];
#pragma unroll
        for (int u = 0; u < 8; ++u) {
          int ku = k + u;
          int s = __shfl(cs, ku & 63);
          float dv = __shfl(cd, ku & 63);
          w[u] = (ku < cc) ? dv : 0.f;
          g[u] = *(const float4*)(x + (size_t)s * FDIM + f);
        }
#pragma unroll
        for (int u = 0; u < 8; ++u) {
          a0 = fmaf(w[u], g[u].x, a0);
          a1 = fmaf(w[u], g[u].y, a1);
          a2 = fmaf(w[u], g[u].z, a2);
          a3 = fmaf(w[u], g[u].w, a3);
        }
      }
    }
    ushort4 o;
    o.x = f2bf(a0 * di); o.y = f2bf(a1 * di); o.z = f2bf(a2 * di); o.w = f2bf(a3 * di);
    *(ushort4*)(out + (size_t)i * FDIM + f) = o;
  }
}

// ---------------- in-place GEMM: buf = bf16( (buf @ W1 + b1) * dis[m] ) ----------------

__global__ __launch_bounds__(256) void gemm_bias_k(
    const unsigned short* __restrict__ A, const unsigned short* __restrict__ BT,
    const float* __restrict__ bias, const float* __restrict__ dis,
    unsigned short* __restrict__ out, int M) {
  __shared__ __align__(16) unsigned short Asm[64 * 40];
  __shared__ __align__(16) unsigned short Bsm[256 * 40];
  int t = threadIdx.x;
  int block_m = blockIdx.x * 64;
  int lane = t & 63, wave = t >> 6;
  int q = lane >> 4, rcol = lane & 15;
  floatx4 acc[4][4] = {};

  for (int kk = 0; kk < 256; kk += 32) {
    __syncthreads();
    {
      int arow = t >> 2;
      int cc = (t & 3) * 8;
      uint4 v = {0, 0, 0, 0};
      int gm = block_m + arow;
      if (gm < M) v = *(const uint4*)(A + (size_t)gm * FDIM + kk + cc);
      *(uint4*)(Asm + arow * 40 + cc) = v;
#pragma unroll
      for (int it = 0; it < 4; ++it) {
        int brow = it * 64 + arow;
        uint4 wv = *(const uint4*)(BT + (size_t)brow * FDIM + kk + cc);
        *(uint4*)(Bsm + brow * 40 + cc) = wv;
      }
    }
    __syncthreads();
    short8 af[4], bfr[4];
#pragma unroll
    for (int mt = 0; mt < 4; ++mt)
      af[mt] = *(const short8*)(Asm + (mt * 16 + rcol) * 40 + q * 8);
#pragma unroll
    for (int nt = 0; nt < 4; ++nt)
      bfr[nt] = *(const short8*)(Bsm + (wave * 64 + nt * 16 + rcol) * 40 + q * 8);
#pragma unroll
    for (int mt = 0; mt < 4; ++mt)
#pragma unroll
      for (int nt = 0; nt < 4; ++nt)
        acc[mt][nt] = __builtin_amdgcn_mfma_f32_16x16x32_bf16(af[mt], bfr[nt], acc[mt][nt], 0, 0, 0);
  }

  float bv[4];
#pragma unroll
  for (int nt = 0; nt < 4; ++nt) bv[nt] = bias[wave * 64 + nt * 16 + rcol];
#pragma unroll
  for (int mt = 0; mt < 4; ++mt)
#pragma unroll
    for (int rr = 0; rr < 4; ++rr) {
      int m = block_m + mt * 16 + q * 4 + rr;
      if (m >= M) continue;
      float sc = dis[m];
#pragma unroll
      for (int nt = 0; nt < 4; ++nt) {
        int nn = wave * 64 + nt * 16 + rcol;
        out[(size_t)m * FDIM + nn] = f2bf((acc[mt][nt][rr] + bv[nt]) * sc);
      }
    }
}

// ---------------- conv2 + head + log_softmax, fused; fp32 output ----------------
// gather: readlane/SGPR-base like agg_b_k. head GEMV: Wc transposed to per-output
// rows, bf16, rotated-granule LDS layout (<=2-way bank aliasing), ds_read_b128 +
// float4 xsh reads. softmax: one wave per row via 64-lane shfl_xor reduce.

__global__ __launch_bounds__(256) void conv2_head_k(
    const unsigned short* __restrict__ l1, const int* __restrict__ row_ptr,
    const int* __restrict__ col, const float* __restrict__ dis,
    const float* __restrict__ Wc, const float* __restrict__ bc,
    float* __restrict__ out, int n) {
  __shared__ __align__(16) unsigned short Wsh[FOUT * FDIM];  // 20480 B, rotated granules
  __shared__ __align__(16) float xsh[4][260];                // padded rows: 4-bank offset per nd
  __shared__ float L[4][FOUT];
  __shared__ float bsh[FOUT];
  int t = threadIdx.x;
  // stage Wc -> Wsh[o][k] bf16; granule g = (k/8 + o) & 31 rotation kills same-bank columns
  for (int c = t; c < FDIM * FOUT; c += 256) {
    int k = c / FOUT, o = c - k * FOUT;
    int g = ((k >> 3) + o) & 31;
    Wsh[o * FDIM + (g << 3) + (k & 7)] = f2bf(Wc[c]);
  }
  if (t < FOUT) bsh[t] = bc[t];
  int wave = t >> 6, lane = t & 63;
  int f = lane * 4;
  bool gv = t < 4 * FOUT;
  int nd = 0, oo = 0;
  if (gv) { nd = t / FOUT; oo = t - nd * FOUT; }
  int step = gridDim.x * 4;
  for (int base = blockIdx.x * 4; base < n; base += step) {
    int i = base + wave;
    __syncthreads();
    if (i < n) {
      ushort4 v = *(const ushort4*)(l1 + (size_t)i * FDIM + f);
      float a0 = bf2f(v.x), a1 = bf2f(v.y), a2 = bf2f(v.z), a3 = bf2f(v.w);
      int beg = row_ptr[i], end = row_ptr[i + 1];
      for (int j0 = beg; j0 < end; j0 += 64) {
        int jj = j0 + lane;
        int cs = (jj < end) ? col[jj] : 0;
        int cc = min(64, end - j0);
        int kf = cc & ~7;
        for (int k = 0; k < kf; k += 8) {
          int sl[8];
#pragma unroll
          for (int u = 0; u < 8; ++u) sl[u] = __builtin_amdgcn_readlane(cs, k + u);
          ushort4 g[8];
#pragma unroll
          for (int u = 0; u < 8; ++u)
            g[u] = *(const ushort4*)(l1 + (size_t)sl[u] * FDIM + f);
#pragma unroll
          for (int u = 0; u < 8; ++u) {
            a0 += bf2f(g[u].x); a1 += bf2f(g[u].y);
            a2 += bf2f(g[u].z); a3 += bf2f(g[u].w);
          }
        }
        if (kf < cc) {
          int sl[8]; float w[8];
#pragma unroll
          for (int u = 0; u < 8; ++u) {
            int ku = kf + u;
            sl[u] = __builtin_amdgcn_readlane(cs, ku & 63);
            w[u] = (ku < cc) ? 1.f : 0.f;
          }
          ushort4 g[8];
#pragma unroll
          for (int u = 0; u < 8; ++u)
            g[u] = *(const ushort4*)(l1 + (size_t)sl[u] * FDIM + f);
#pragma unroll
          for (int u = 0; u < 8; ++u) {
            a0 = fmaf(w[u], bf2f(g[u].x), a0);
            a1 = fmaf(w[u], bf2f(g[u].y), a1);
            a2 = fmaf(w[u], bf2f(g[u].z), a2);
            a3 = fmaf(w[u], bf2f(g[u].w), a3);
          }
        }
      }
      float di = dis[i];
      float4 xv = {a0 * di, a1 * di, a2 * di, a3 * di};
      *(float4*)&xsh[wave][f] = xv;
    }
    __syncthreads();
    if (gv) {
      float acc = bsh[oo];
      const unsigned short* wr = Wsh + oo * FDIM;
      const float* xr = xsh[nd];
#pragma unroll 4
      for (int kg = 0; kg < 32; ++kg) {
        int gg = (kg + oo) & 31;
        short8 wv = *(const short8*)(wr + (gg << 3));
        int k = kg << 3;
        float4 x0 = *(const float4*)(xr + k);
        float4 x1 = *(const float4*)(xr + k + 4);
        acc = fmaf(x0.x, bf2f((unsigned short)wv[0]), acc);
        acc = fmaf(x0.y, bf2f((unsigned short)wv[1]), acc);
        acc = fmaf(x0.z, bf2f((unsigned short)wv[2]), acc);
        acc = fmaf(x0.w, bf2f((unsigned short)wv[3]), acc);
        acc = fmaf(x1.x, bf2f((unsigned short)wv[4]), acc);
        acc = fmaf(x1.y, bf2f((unsigned short)wv[5]), acc);
        acc = fmaf(x1.z, bf2f((unsigned short)wv[6]), acc);
        acc = fmaf(x1.w, bf2f((unsigned short)wv[7]), acc);
      }
      L[nd][oo] = acc;
    }
    __syncthreads();
    if (i < n) {
      float v = (lane < FOUT) ? L[wave][lane] : -3.4e38f;
      float m = v;
#pragma unroll
      for (int off = 32; off; off >>= 1) m = fmaxf(m, __shfl_xor(m, off));
      float e = (lane < FOUT) ? __expf(v - m) : 0.f;
      float s = e;
#pragma unroll
      for (int off = 32; off; off >>= 1) s += __shfl_xor(s, off);
      float lg = m + __logf(s);
      if (lane < FOUT) out[(size_t)i * FOUT + lane] = v - lg;
    }
  }
}

// ---------------- launch ----------------

extern "C" void kernel_launch(void* const* d_in, const int* in_sizes, int n_in,
                              void* d_out, int out_size, void* d_ws, size_t ws_size,
                              hipStream_t stream) {
  const float* x   = (const float*)d_in[0];
  const int* eraw  = (const int*)d_in[1];
  const float* W1  = (const float*)d_in[2];
  const float* b1  = (const float*)d_in[3];
  const float* W2  = (const float*)d_in[4];
  const float* b2  = (const float*)d_in[5];
  const float* Wl  = (const float*)d_in[6];
  const float* bl  = (const float*)d_in[7];
  float* out = (float*)d_out;

  const int N = in_sizes[0] / FDIM;
  const int E = in_sizes[1] / 2;

  char* w = (char*)d_ws;
  size_t off = 0;
  auto take = [&](size_t bytes) {
    void* p = w + off;
    off = (off + bytes + 255) & ~(size_t)255;
    return p;
  };
  int* cnt     = (int*)take((size_t)N * 4);
  int* cursor  = (int*)take((size_t)N * 4);
  int* row_ptr = (int*)take((size_t)(N + 1) * 4);
  float* dis   = (float*)take((size_t)N * 4);
  int* bsum    = (int*)take(4096);
  int* eflag   = (int*)take(256);
  unsigned short* W1T = (unsigned short*)take((size_t)FDIM * FDIM * 2);
  float* Wc    = (float*)take((size_t)FDIM * FOUT * 4);
  float* bc    = (float*)take(FOUT * 4);
  int* colx    = (int*)take((size_t)E * 4);
  size_t pairBytes = (size_t)2 * E * 4;
  size_t bufBytes  = (size_t)N * FDIM * 2;
  size_t r1Bytes = bufBytes > pairBytes ? bufBytes : pairBytes;
  void* region1 = take(r1Bytes);
  unsigned short* buf = (unsigned short*)region1;
  // big path: xs (bf16 pre-folded x) lives in its own region, which also hosts srcN/dstN early
  size_t xsBytes = (size_t)N * FDIM * 2;
  size_t xsRegion = xsBytes > pairBytes ? xsBytes : pairBytes;
  bool big = (off + xsRegion) <= ws_size;
  unsigned short* xs = nullptr;
  int* srcN;
  if (big) {
    xs = (unsigned short*)take(xsRegion);
    srcN = (int*)xs;
  } else {
    srcN = (int*)region1;  // union with buf (dead before agg writes buf)
  }
  int* dstN = srcN + E;
  (void)n_in; (void)out_size;

  int gE = (E + 255) / 256;
  int gN = (N + 255) / 256;
  int NB = (N + 1023) / 1024;
  int gG = (N + 63) / 64;

  int probe_words = 65536 < 2 * E ? 65536 : 2 * E;
  hipLaunchKernelGGL(detect_k, dim3(1), dim3(256), 0, stream, eraw, probe_words, eflag);
  hipLaunchKernelGGL(normalize_k, dim3(gE), dim3(256), 0, stream, eraw, eflag, srcN, dstN, E);

  hipLaunchKernelGGL(zero_cnt_k, dim3(gN), dim3(256), 0, stream, cnt, N);
  hipLaunchKernelGGL(count_k, dim3(gE), dim3(256), 0, stream, dstN, cnt, E, N);
  hipLaunchKernelGGL(dis_k, dim3(gN), dim3(256), 0, stream, cnt, dis, N);
  hipLaunchKernelGGL(scan_a_k, dim3(NB), dim3(1024), 0, stream, cnt, row_ptr, bsum, N);
  hipLaunchKernelGGL(scan_b_k, dim3(1), dim3(1024), 0, stream, bsum, NB);
  hipLaunchKernelGGL(scan_c_k, dim3(NB), dim3(1024), 0, stream, row_ptr, bsum, cnt, cursor, N);
  hipLaunchKernelGGL(fill_k, dim3(gE), dim3(256), 0, stream, srcN, dstN, cursor, colx, E, N);
  hipLaunchKernelGGL(transp_k, dim3(FDIM), dim3(FDIM), 0, stream, W1, W1T);
  hipLaunchKernelGGL(wc_k, dim3(FDIM), dim3(64), 0, stream, W2, Wl, Wc);
  hipLaunchKernelGGL(bc_k, dim3(1), dim3(64), 0, stream, b2, Wl, bl, bc);

  // layer 1: z = dis_i*(sum of pre-folded rows); in-place GEMM folds bias and dis for layer 2
  if (big) {
    hipLaunchKernelGGL(fold_k, dim3(2048), dim3(256), 0, stream, x, dis, xs, N);
    hipLaunchKernelGGL(agg_b_k, dim3(2048), dim3(256), 0, stream,
                       xs, row_ptr, colx, dis, buf, N);
  } else {
    hipLaunchKernelGGL(agg_f_k, dim3(2048), dim3(256), 0, stream,
                       x, row_ptr, colx, dis, buf, N);
  }
  hipLaunchKernelGGL(gemm_bias_k, dim3(gG), dim3(256), 0, stream, buf, W1T, b1, dis, buf, N);
  hipLaunchKernelGGL(conv2_head_k, dim3(2048), dim3(256), 0, stream,
                     buf, row_ptr, colx, dis, Wc, bc, out, N);
}

// Round 2
// 928.446 us; speedup vs baseline: 1.2665x; 1.2402x over previous
//
#include <hip/hip_runtime.h>
#include <hip/hip_bf16.h>

#define FDIM 256
#define FOUT 40
#define RPB 256   // rows per bucket in CSR-build binning

typedef __attribute__((ext_vector_type(8))) short short8;
typedef __attribute__((ext_vector_type(4))) float floatx4;

__device__ __forceinline__ float bf2f(unsigned short u) {
  unsigned int x = ((unsigned int)u) << 16;
  float f;
  __builtin_memcpy(&f, &x, 4);
  return f;
}
__device__ __forceinline__ unsigned short f2bf(float f) {
  __hip_bfloat16 h = __float2bfloat16(f);
  unsigned short u;
  __builtin_memcpy(&u, &h, 2);
  return u;
}

// ---------------- edge_index layout detection + normalization ----------------

__global__ void detect_k(const int* __restrict__ raw, int nwords, int* __restrict__ flag) {
  if (threadIdx.x == 0) *flag = 0;
  __syncthreads();
  int found = 0;
  for (int w = 1 + 2 * threadIdx.x; w < nwords; w += 512)
    if (raw[w] != 0) { found = 1; break; }
  if (found) atomicOr(flag, 1);  // 1 => int32 layout
}

__global__ void normalize_k(const int* __restrict__ raw, const int* __restrict__ flag,
                            int* __restrict__ srcN, int* __restrict__ dstN, int e) {
  int i = blockIdx.x * 256 + threadIdx.x;
  if (i >= e) return;
  if (*flag) {
    srcN[i] = raw[i];
    dstN[i] = raw[e + i];
  } else {
    srcN[i] = raw[2 * i];
    dstN[i] = raw[2 * (e + i)];
  }
}

// ---------------- CSR build ----------------

__global__ void zero_cnt_k(int* cnt, int n) {
  int i = blockIdx.x * 256 + threadIdx.x;
  if (i < n) cnt[i] = 0;
}

__global__ void count_k(const int* __restrict__ dst, int* __restrict__ cnt, int e, int n) {
  int i = blockIdx.x * 256 + threadIdx.x;
  if (i < e) {
    int d = dst[i];
    if (d >= 0 && d < n) atomicAdd(&cnt[d], 1);
  }
}

__global__ void dis_k(const int* __restrict__ cnt, float* __restrict__ dis, int n) {
  int i = blockIdx.x * 256 + threadIdx.x;
  if (i < n) dis[i] = rsqrtf((float)cnt[i] + 1.0f);
}

__global__ void scan_a_k(const int* __restrict__ cnt, int* __restrict__ excl,
                         int* __restrict__ bsum, int n) {
  __shared__ int sh[1024];
  int t = threadIdx.x;
  int gid = blockIdx.x * 1024 + t;
  int v = (gid < n) ? cnt[gid] : 0;
  sh[t] = v;
  __syncthreads();
  for (int off = 1; off < 1024; off <<= 1) {
    int x = (t >= off) ? sh[t - off] : 0;
    __syncthreads();
    sh[t] += x;
    __syncthreads();
  }
  if (gid < n) excl[gid] = sh[t] - v;
  if (t == 1023) bsum[blockIdx.x] = sh[1023];
}

__global__ void scan_b_k(int* __restrict__ bsum, int nb) {
  __shared__ int sh[1024];
  int t = threadIdx.x;
  int v = (t < nb) ? bsum[t] : 0;
  sh[t] = v;
  __syncthreads();
  for (int off = 1; off < 1024; off <<= 1) {
    int x = (t >= off) ? sh[t - off] : 0;
    __syncthreads();
    sh[t] += x;
    __syncthreads();
  }
  if (t < nb) bsum[t] = sh[t] - v;
}

__global__ void scan_c_k(int* __restrict__ row_ptr, const int* __restrict__ bsum,
                         const int* __restrict__ cnt, int* __restrict__ cursor, int n) {
  int gid = blockIdx.x * 1024 + threadIdx.x;
  if (gid < n) {
    int r = row_ptr[gid] + bsum[blockIdx.x];
    row_ptr[gid] = r;
    cursor[gid] = r;
    if (gid == n - 1) row_ptr[n] = r + cnt[gid];
  }
}

// legacy single-pass scatter (fallback for N > 2^17)
__global__ void fill_k(const int* __restrict__ src, const int* __restrict__ dst,
                       int* __restrict__ cursor, int* __restrict__ col, int e, int n) {
  int i = blockIdx.x * 256 + threadIdx.x;
  if (i < e) {
    int d = dst[i];
    if (d >= 0 && d < n) {
      int slot = atomicAdd(&cursor[d], 1);
      int s = src[i];
      s = min(max(s, 0), n - 1);
      col[slot] = s;
    }
  }
}

// ---- bucketed CSR fill: bucket = dst>>8 (256 rows); row_ptr gives bucket bases ----

__global__ void bcinit_k(const int* __restrict__ row_ptr, int* __restrict__ bcur,
                         int n, int nbuck) {
  int b = blockIdx.x * 256 + threadIdx.x;
  if (b < nbuck) {
    int r = b * RPB;
    if (r > n) r = n;
    bcur[b] = row_ptr[r];
  }
}

// pass A: bin edges into per-bucket contiguous regions; payload packs (dst&255, src)
__global__ __launch_bounds__(1024) void bin_k(
    const int* __restrict__ src, const int* __restrict__ dst,
    int* __restrict__ bcur, unsigned int* __restrict__ binned,
    int e, int n, int nbuck, int cpb) {
  __shared__ int hist[512];
  __shared__ int base_[512];
  __shared__ int cnt2[512];
  int t = threadIdx.x;
  int start = blockIdx.x * cpb;
  int endc = min(e, start + cpb);
  for (int b = t; b < nbuck; b += 1024) { hist[b] = 0; cnt2[b] = 0; }
  __syncthreads();
  for (int i = start + t; i < endc; i += 1024) {
    int d = dst[i];
    if (d >= 0 && d < n) atomicAdd(&hist[d >> 8], 1);
  }
  __syncthreads();
  for (int b = t; b < nbuck; b += 1024) {
    int h = hist[b];
    base_[b] = h ? atomicAdd(&bcur[b], h) : 0;
  }
  __syncthreads();
  for (int i = start + t; i < endc; i += 1024) {
    int d = dst[i];
    if (d >= 0 && d < n) {
      int bk = d >> 8;
      int s = src[i];
      s = min(max(s, 0), n - 1);
      int pos = base_[bk] + atomicAdd(&cnt2[bk], 1);
      binned[pos] = (((unsigned int)(d & 255)) << 17) | (unsigned int)s;
    }
  }
}

// pass B: per-bucket scatter with LDS row cursors; col writes stay in a 32KB window
__global__ __launch_bounds__(256) void scat_k(
    const unsigned int* __restrict__ binned, const int* __restrict__ row_ptr,
    int* __restrict__ col, int n) {
  __shared__ int cur[RPB];
  int b = blockIdx.x;
  int r0 = b * RPB;
  int r1 = min(n, r0 + RPB);
  int t = threadIdx.x;
  if (r0 + t < r1) cur[t] = row_ptr[r0 + t];
  __syncthreads();
  int e0 = row_ptr[r0];
  int e1 = row_ptr[r1];
  for (int i = e0 + t; i < e1; i += 256) {
    unsigned int p = binned[i];
    int dlow = (int)(p >> 17);
    int slot = atomicAdd(&cur[dlow], 1);
    col[slot] = (int)(p & 0x1FFFF);
  }
}

// ---------------- W1T: bf16 transpose of fp32 W1 ----------------

__global__ void transp_k(const float* __restrict__ in, unsigned short* __restrict__ out) {
  out[(size_t)blockIdx.x * FDIM + threadIdx.x] =
      f2bf(in[(size_t)threadIdx.x * FDIM + blockIdx.x]);
}

// ---------------- Wc = W2 @ Wlin (fp32); bc = b2 @ Wlin + blin ----------------

__global__ __launch_bounds__(64) void wc_k(const float* __restrict__ W2,
                                           const float* __restrict__ Wlin,
                                           float* __restrict__ Wc) {
  __shared__ float row[FDIM];
  int k = blockIdx.x, t = threadIdx.x;
  for (int j = t; j < FDIM; j += 64) row[j] = W2[(size_t)k * FDIM + j];
  __syncthreads();
  if (t < FOUT) {
    float acc = 0.f;
    for (int j = 0; j < FDIM; ++j) acc += row[j] * Wlin[(size_t)j * FOUT + t];
    Wc[(size_t)k * FOUT + t] = acc;
  }
}

__global__ __launch_bounds__(64) void bc_k(const float* __restrict__ b2,
                                           const float* __restrict__ Wlin,
                                           const float* __restrict__ blin,
                                           float* __restrict__ bc) {
  int t = threadIdx.x;
  if (t < FOUT) {
    float acc = blin[t];
    for (int j = 0; j < FDIM; ++j) acc += b2[j] * Wlin[(size_t)j * FOUT + t];
    bc[t] = acc;
  }
}

// ---------------- xs = bf16(x * dis[row]) ----------------

__global__ __launch_bounds__(256) void fold_k(const float* __restrict__ x,
                                              const float* __restrict__ dis,
                                              unsigned short* __restrict__ xs, int n) {
  int total = n * (FDIM / 4);
  for (int idx = blockIdx.x * 256 + threadIdx.x; idx < total; idx += gridDim.x * 256) {
    int row = idx >> 6;
    float di = dis[row];
    float4 v = *(const float4*)(x + (size_t)idx * 4);
    ushort4 o;
    o.x = f2bf(v.x * di); o.y = f2bf(v.y * di); o.z = f2bf(v.z * di); o.w = f2bf(v.w * di);
    *(ushort4*)(xs + (size_t)idx * 4) = o;
  }
}

// ---------------- agg over bf16 pre-folded table ----------------

__global__ __launch_bounds__(256) void agg_b_k(
    const unsigned short* __restrict__ tab, const int* __restrict__ row_ptr,
    const int* __restrict__ col, const float* __restrict__ dis,
    unsigned short* __restrict__ out, int n) {
  int wave = threadIdx.x >> 6, lane = threadIdx.x & 63;
  int wid = blockIdx.x * 4 + wave;
  int nw = gridDim.x * 4;
  int f = lane * 4;
  for (int i = wid; i < n; i += nw) {
    ushort4 v = *(const ushort4*)(tab + (size_t)i * FDIM + f);
    float a0 = bf2f(v.x), a1 = bf2f(v.y), a2 = bf2f(v.z), a3 = bf2f(v.w);
    int beg = row_ptr[i], end = row_ptr[i + 1];
    for (int j0 = beg; j0 < end; j0 += 64) {
      int jj = j0 + lane;
      int cs = (jj < end) ? col[jj] : 0;
      int cc = min(64, end - j0);
      int kf = cc & ~7;
      for (int k = 0; k < kf; k += 8) {
        int sl[8];
#pragma unroll
        for (int u = 0; u < 8; ++u) sl[u] = __builtin_amdgcn_readlane(cs, k + u);
        ushort4 g[8];
#pragma unroll
        for (int u = 0; u < 8; ++u)
          g[u] = *(const ushort4*)(tab + (size_t)sl[u] * FDIM + f);
#pragma unroll
        for (int u = 0; u < 8; ++u) {
          a0 += bf2f(g[u].x); a1 += bf2f(g[u].y);
          a2 += bf2f(g[u].z); a3 += bf2f(g[u].w);
        }
      }
      if (kf < cc) {
        int sl[8]; float w[8];
#pragma unroll
        for (int u = 0; u < 8; ++u) {
          int ku = kf + u;
          sl[u] = __builtin_amdgcn_readlane(cs, ku & 63);
          w[u] = (ku < cc) ? 1.f : 0.f;
        }
        ushort4 g[8];
#pragma unroll
        for (int u = 0; u < 8; ++u)
          g[u] = *(const ushort4*)(tab + (size_t)sl[u] * FDIM + f);
#pragma unroll
        for (int u = 0; u < 8; ++u) {
          a0 = fmaf(w[u], bf2f(g[u].x), a0);
          a1 = fmaf(w[u], bf2f(g[u].y), a1);
          a2 = fmaf(w[u], bf2f(g[u].z), a2);
          a3 = fmaf(w[u], bf2f(g[u].w), a3);
        }
      }
    }
    float di = dis[i];
    ushort4 o;
    o.x = f2bf(a0 * di); o.y = f2bf(a1 * di); o.z = f2bf(a2 * di); o.w = f2bf(a3 * di);
    *(ushort4*)(out + (size_t)i * FDIM + f) = o;
  }
}

// ---------------- fallback: agg over fp32 x with per-edge dis weight ----------------

__global__ __launch_bounds__(256) void agg_f_k(
    const float* __restrict__ x, const int* __restrict__ row_ptr,
    const int* __restrict__ col, const float* __restrict__ dis,
    unsigned short* __restrict__ out, int n) {
  int wave = threadIdx.x >> 6, lane = threadIdx.x & 63;
  int wid = blockIdx.x * 4 + wave;
  int nw = gridDim.x * 4;
  for (int i = wid; i < n; i += nw) {
    int f = lane * 4;
    float di = dis[i];
    float4 v = *(const float4*)(x + (size_t)i * FDIM + f);
    float a0 = v.x * di, a1 = v.y * di, a2 = v.z * di, a3 = v.w * di;
    int beg = row_ptr[i], end = row_ptr[i + 1];
    for (int j0 = beg; j0 < end; j0 += 64) {
      int jj = j0 + lane;
      int cs = (jj < end) ? col[jj] : 0;
      float cd = (jj < end) ? dis[cs] : 0.f;
      int cc = min(64, end - j0);
      for (int k = 0; k < cc; k += 8) {
        float4 g[8];
        float w[8];
#pragma unroll
        for (int u = 0; u < 8; ++u) {
          int ku = k + u;
          int s = __shfl(cs, ku & 63);
          float dv = __shfl(cd, ku & 63);
          w[u] = (ku < cc) ? dv : 0.f;
          g[u] = *(const float4*)(x + (size_t)s * FDIM + f);
        }
#pragma unroll
        for (int u = 0; u < 8; ++u) {
          a0 = fmaf(w[u], g[u].x, a0);
          a1 = fmaf(w[u], g[u].y, a1);
          a2 = fmaf(w[u], g[u].z, a2);
          a3 = fmaf(w[u], g[u].w, a3);
        }
      }
    }
    ushort4 o;
    o.x = f2bf(a0 * di); o.y = f2bf(a1 * di); o.z = f2bf(a2 * di); o.w = f2bf(a3 * di);
    *(ushort4*)(out + (size_t)i * FDIM + f) = o;
  }
}

// ---------------- in-place GEMM: buf = bf16( (buf @ W1 + b1) * dis[m] ) ----------------

__global__ __launch_bounds__(256) void gemm_bias_k(
    const unsigned short* __restrict__ A, const unsigned short* __restrict__ BT,
    const float* __restrict__ bias, const float* __restrict__ dis,
    unsigned short* __restrict__ out, int M) {
  __shared__ __align__(16) unsigned short Asm[64 * 40];
  __shared__ __align__(16) unsigned short Bsm[256 * 40];
  int t = threadIdx.x;
  int block_m = blockIdx.x * 64;
  int lane = t & 63, wave = t >> 6;
  int q = lane >> 4, rcol = lane & 15;
  floatx4 acc[4][4] = {};

  for (int kk = 0; kk < 256; kk += 32) {
    __syncthreads();
    {
      int arow = t >> 2;
      int cc = (t & 3) * 8;
      uint4 v = {0, 0, 0, 0};
      int gm = block_m + arow;
      if (gm < M) v = *(const uint4*)(A + (size_t)gm * FDIM + kk + cc);
      *(uint4*)(Asm + arow * 40 + cc) = v;
#pragma unroll
      for (int it = 0; it < 4; ++it) {
        int brow = it * 64 + arow;
        uint4 wv = *(const uint4*)(BT + (size_t)brow * FDIM + kk + cc);
        *(uint4*)(Bsm + brow * 40 + cc) = wv;
      }
    }
    __syncthreads();
    short8 af[4], bfr[4];
#pragma unroll
    for (int mt = 0; mt < 4; ++mt)
      af[mt] = *(const short8*)(Asm + (mt * 16 + rcol) * 40 + q * 8);
#pragma unroll
    for (int nt = 0; nt < 4; ++nt)
      bfr[nt] = *(const short8*)(Bsm + (wave * 64 + nt * 16 + rcol) * 40 + q * 8);
#pragma unroll
    for (int mt = 0; mt < 4; ++mt)
#pragma unroll
      for (int nt = 0; nt < 4; ++nt)
        acc[mt][nt] = __builtin_amdgcn_mfma_f32_16x16x32_bf16(af[mt], bfr[nt], acc[mt][nt], 0, 0, 0);
  }

  float bv[4];
#pragma unroll
  for (int nt = 0; nt < 4; ++nt) bv[nt] = bias[wave * 64 + nt * 16 + rcol];
#pragma unroll
  for (int mt = 0; mt < 4; ++mt)
#pragma unroll
    for (int rr = 0; rr < 4; ++rr) {
      int m = block_m + mt * 16 + q * 4 + rr;
      if (m >= M) continue;
      float sc = dis[m];
#pragma unroll
      for (int nt = 0; nt < 4; ++nt) {
        int nn = wave * 64 + nt * 16 + rcol;
        out[(size_t)m * FDIM + nn] = f2bf((acc[mt][nt][rr] + bv[nt]) * sc);
      }
    }
}

// ---------------- conv2 + head + log_softmax, fused; fp32 output ----------------

__global__ __launch_bounds__(256) void conv2_head_k(
    const unsigned short* __restrict__ l1, const int* __restrict__ row_ptr,
    const int* __restrict__ col, const float* __restrict__ dis,
    const float* __restrict__ Wc, const float* __restrict__ bc,
    float* __restrict__ out, int n) {
  __shared__ __align__(16) unsigned short Wsh[FOUT * FDIM];  // 20480 B, rotated granules
  __shared__ __align__(16) float xsh[4][260];
  __shared__ float L[4][FOUT];
  __shared__ float bsh[FOUT];
  int t = threadIdx.x;
  for (int c = t; c < FDIM * FOUT; c += 256) {
    int k = c / FOUT, o = c - k * FOUT;
    int g = ((k >> 3) + o) & 31;
    Wsh[o * FDIM + (g << 3) + (k & 7)] = f2bf(Wc[c]);
  }
  if (t < FOUT) bsh[t] = bc[t];
  int wave = t >> 6, lane = t & 63;
  int f = lane * 4;
  bool gv = t < 4 * FOUT;
  int nd = 0, oo = 0;
  if (gv) { nd = t / FOUT; oo = t - nd * FOUT; }
  int step = gridDim.x * 4;
  for (int base = blockIdx.x * 4; base < n; base += step) {
    int i = base + wave;
    __syncthreads();
    if (i < n) {
      ushort4 v = *(const ushort4*)(l1 + (size_t)i * FDIM + f);
      float a0 = bf2f(v.x), a1 = bf2f(v.y), a2 = bf2f(v.z), a3 = bf2f(v.w);
      int beg = row_ptr[i], end = row_ptr[i + 1];
      for (int j0 = beg; j0 < end; j0 += 64) {
        int jj = j0 + lane;
        int cs = (jj < end) ? col[jj] : 0;
        int cc = min(64, end - j0);
        int kf = cc & ~7;
        for (int k = 0; k < kf; k += 8) {
          int sl[8];
#pragma unroll
          for (int u = 0; u < 8; ++u) sl[u] = __builtin_amdgcn_readlane(cs, k + u);
          ushort4 g[8];
#pragma unroll
          for (int u = 0; u < 8; ++u)
            g[u] = *(const ushort4*)(l1 + (size_t)sl[u] * FDIM + f);
#pragma unroll
          for (int u = 0; u < 8; ++u) {
            a0 += bf2f(g[u].x); a1 += bf2f(g[u].y);
            a2 += bf2f(g[u].z); a3 += bf2f(g[u].w);
          }
        }
        if (kf < cc) {
          int sl[8]; float w[8];
#pragma unroll
          for (int u = 0; u < 8; ++u) {
            int ku = kf + u;
            sl[u] = __builtin_amdgcn_readlane(cs, ku & 63);
            w[u] = (ku < cc) ? 1.f : 0.f;
          }
          ushort4 g[8];
#pragma unroll
          for (int u = 0; u < 8; ++u)
            g[u] = *(const ushort4*)(l1 + (size_t)sl[u] * FDIM + f);
#pragma unroll
          for (int u = 0; u < 8; ++u) {
            a0 = fmaf(w[u], bf2f(g[u].x), a0);
            a1 = fmaf(w[u], bf2f(g[u].y), a1);
            a2 = fmaf(w[u], bf2f(g[u].z), a2);
            a3 = fmaf(w[u], bf2f(g[u].w), a3);
          }
        }
      }
      float di = dis[i];
      float4 xv = {a0 * di, a1 * di, a2 * di, a3 * di};
      *(float4*)&xsh[wave][f] = xv;
    }
    __syncthreads();
    if (gv) {
      float acc = bsh[oo];
      const unsigned short* wr = Wsh + oo * FDIM;
      const float* xr = xsh[nd];
#pragma unroll 4
      for (int kg = 0; kg < 32; ++kg) {
        int gg = (kg + oo) & 31;
        short8 wv = *(const short8*)(wr + (gg << 3));
        int k = kg << 3;
        float4 x0 = *(const float4*)(xr + k);
        float4 x1 = *(const float4*)(xr + k + 4);
        acc = fmaf(x0.x, bf2f((unsigned short)wv[0]), acc);
        acc = fmaf(x0.y, bf2f((unsigned short)wv[1]), acc);
        acc = fmaf(x0.z, bf2f((unsigned short)wv[2]), acc);
        acc = fmaf(x0.w, bf2f((unsigned short)wv[3]), acc);
        acc = fmaf(x1.x, bf2f((unsigned short)wv[4]), acc);
        acc = fmaf(x1.y, bf2f((unsigned short)wv[5]), acc);
        acc = fmaf(x1.z, bf2f((unsigned short)wv[6]), acc);
        acc = fmaf(x1.w, bf2f((unsigned short)wv[7]), acc);
      }
      L[nd][oo] = acc;
    }
    __syncthreads();
    if (i < n) {
      float v = (lane < FOUT) ? L[wave][lane] : -3.4e38f;
      float m = v;
#pragma unroll
      for (int off = 32; off; off >>= 1) m = fmaxf(m, __shfl_xor(m, off));
      float e = (lane < FOUT) ? __expf(v - m) : 0.f;
      float s = e;
#pragma unroll
      for (int off = 32; off; off >>= 1) s += __shfl_xor(s, off);
      float lg = m + __logf(s);
      if (lane < FOUT) out[(size_t)i * FOUT + lane] = v - lg;
    }
  }
}

// ---------------- launch ----------------

extern "C" void kernel_launch(void* const* d_in, const int* in_sizes, int n_in,
                              void* d_out, int out_size, void* d_ws, size_t ws_size,
                              hipStream_t stream) {
  const float* x   = (const float*)d_in[0];
  const int* eraw  = (const int*)d_in[1];
  const float* W1  = (const float*)d_in[2];
  const float* b1  = (const float*)d_in[3];
  const float* W2  = (const float*)d_in[4];
  const float* b2  = (const float*)d_in[5];
  const float* Wl  = (const float*)d_in[6];
  const float* bl  = (const float*)d_in[7];
  float* out = (float*)d_out;

  const int N = in_sizes[0] / FDIM;
  const int E = in_sizes[1] / 2;

  char* w = (char*)d_ws;
  size_t off = 0;
  auto take = [&](size_t bytes) {
    void* p = w + off;
    off = (off + bytes + 255) & ~(size_t)255;
    return p;
  };
  int* cnt     = (int*)take((size_t)N * 4);
  int* cursor  = (int*)take((size_t)N * 4);   // doubles as per-bucket cursor in new path
  int* row_ptr = (int*)take((size_t)(N + 1) * 4);
  float* dis   = (float*)take((size_t)N * 4);
  int* bsum    = (int*)take(4096);
  int* eflag   = (int*)take(256);
  unsigned short* W1T = (unsigned short*)take((size_t)FDIM * FDIM * 2);
  float* Wc    = (float*)take((size_t)FDIM * FOUT * 4);
  float* bc    = (float*)take(FOUT * 4);
  int* colx    = (int*)take((size_t)E * 4);
  size_t pairBytes = (size_t)2 * E * 4;
  size_t bufBytes  = (size_t)N * FDIM * 2;
  size_t r1Bytes = bufBytes > pairBytes ? bufBytes : pairBytes;
  void* region1 = take(r1Bytes);
  unsigned short* buf = (unsigned short*)region1;
  size_t xsBytes = (size_t)N * FDIM * 2;
  size_t xsRegion = xsBytes > pairBytes ? xsBytes : pairBytes;
  bool big = (off + xsRegion) <= ws_size;
  unsigned short* xs = nullptr;
  int* srcN;
  if (big) {
    xs = (unsigned short*)take(xsRegion);
    srcN = (int*)xs;
  } else {
    srcN = (int*)region1;  // union with buf (dead before agg writes buf)
  }
  int* dstN = srcN + E;
  (void)n_in; (void)out_size;

  int gE = (E + 255) / 256;
  int gN = (N + 255) / 256;
  int NB = (N + 1023) / 1024;
  int gG = (N + 63) / 64;
  int nbuck = (N + RPB - 1) / RPB;

  // bucketed fill needs: big-path layout (binned fits after srcN/dstN in xs region),
  // src packs in 17 bits, bucket count fits LDS arrays
  bool bucketed = big && (N <= (1 << 17)) &&
                  (pairBytes + (size_t)E * 4 <= xsRegion);
  unsigned int* binned = (unsigned int*)((char*)xs + pairBytes);

  int probe_words = 65536 < 2 * E ? 65536 : 2 * E;
  hipLaunchKernelGGL(detect_k, dim3(1), dim3(256), 0, stream, eraw, probe_words, eflag);
  hipLaunchKernelGGL(normalize_k, dim3(gE), dim3(256), 0, stream, eraw, eflag, srcN, dstN, E);

  hipLaunchKernelGGL(zero_cnt_k, dim3(gN), dim3(256), 0, stream, cnt, N);
  hipLaunchKernelGGL(count_k, dim3(gE), dim3(256), 0, stream, dstN, cnt, E, N);
  hipLaunchKernelGGL(dis_k, dim3(gN), dim3(256), 0, stream, cnt, dis, N);
  hipLaunchKernelGGL(scan_a_k, dim3(NB), dim3(1024), 0, stream, cnt, row_ptr, bsum, N);
  hipLaunchKernelGGL(scan_b_k, dim3(1), dim3(1024), 0, stream, bsum, NB);
  hipLaunchKernelGGL(scan_c_k, dim3(NB), dim3(1024), 0, stream, row_ptr, bsum, cnt, cursor, N);
  if (bucketed) {
    int nblk = 256;
    int cpb = (E + nblk - 1) / nblk;
    hipLaunchKernelGGL(bcinit_k, dim3((nbuck + 255) / 256), dim3(256), 0, stream,
                       row_ptr, cursor, N, nbuck);
    hipLaunchKernelGGL(bin_k, dim3(nblk), dim3(1024), 0, stream,
                       srcN, dstN, cursor, binned, E, N, nbuck, cpb);
    hipLaunchKernelGGL(scat_k, dim3(nbuck), dim3(256), 0, stream,
                       binned, row_ptr, colx, N);
  } else {
    hipLaunchKernelGGL(fill_k, dim3(gE), dim3(256), 0, stream, srcN, dstN, cursor, colx, E, N);
  }
  hipLaunchKernelGGL(transp_k, dim3(FDIM), dim3(FDIM), 0, stream, W1, W1T);
  hipLaunchKernelGGL(wc_k, dim3(FDIM), dim3(64), 0, stream, W2, Wl, Wc);
  hipLaunchKernelGGL(bc_k, dim3(1), dim3(64), 0, stream, b2, Wl, bl, bc);

  if (big) {
    hipLaunchKernelGGL(fold_k, dim3(2048), dim3(256), 0, stream, x, dis, xs, N);
    hipLaunchKernelGGL(agg_b_k, dim3(2048), dim3(256), 0, stream,
                       xs, row_ptr, colx, dis, buf, N);
  } else {
    hipLaunchKernelGGL(agg_f_k, dim3(2048), dim3(256), 0, stream,
                       x, row_ptr, colx, dis, buf, N);
  }
  hipLaunchKernelGGL(gemm_bias_k, dim3(gG), dim3(256), 0, stream, buf, W1T, b1, dis, buf, N);
  hipLaunchKernelGGL(conv2_head_k, dim3(2048), dim3(256), 0, stream,
                     buf, row_ptr, colx, dis, Wc, bc, out, N);
}

// Round 3
// 612.409 us; speedup vs baseline: 1.9201x; 1.5161x over previous
//
#include <hip/hip_runtime.h>
#include <hip/hip_bf16.h>

#define FDIM 256
#define FOUT 40
#define RPB 256   // rows per bucket in CSR-build binning

typedef __attribute__((ext_vector_type(8))) short short8;
typedef __attribute__((ext_vector_type(4))) float floatx4;

__device__ __forceinline__ float bf2f(unsigned short u) {
  unsigned int x = ((unsigned int)u) << 16;
  float f;
  __builtin_memcpy(&f, &x, 4);
  return f;
}
__device__ __forceinline__ unsigned short f2bf(float f) {
  __hip_bfloat16 h = __float2bfloat16(f);
  unsigned short u;
  __builtin_memcpy(&u, &h, 2);
  return u;
}

// ---------------- edge_index layout detection + normalization ----------------

__global__ void detect_k(const int* __restrict__ raw, int nwords, int* __restrict__ flag) {
  if (threadIdx.x == 0) *flag = 0;
  __syncthreads();
  int found = 0;
  for (int w = 1 + 2 * threadIdx.x; w < nwords; w += 512)
    if (raw[w] != 0) { found = 1; break; }
  if (found) atomicOr(flag, 1);  // 1 => int32 layout
}

__global__ void normalize_k(const int* __restrict__ raw, const int* __restrict__ flag,
                            int* __restrict__ srcN, int* __restrict__ dstN, int e) {
  int i = blockIdx.x * 256 + threadIdx.x;
  if (i >= e) return;
  if (*flag) {
    srcN[i] = raw[i];
    dstN[i] = raw[e + i];
  } else {
    srcN[i] = raw[2 * i];
    dstN[i] = raw[2 * (e + i)];
  }
}

// ---------------- CSR build ----------------

__global__ void zero_cnt_k(int* cnt, int n) {
  int i = blockIdx.x * 256 + threadIdx.x;
  if (i < n) cnt[i] = 0;
}

__global__ void count_k(const int* __restrict__ dst, int* __restrict__ cnt, int e, int n) {
  int i = blockIdx.x * 256 + threadIdx.x;
  if (i < e) {
    int d = dst[i];
    if (d >= 0 && d < n) atomicAdd(&cnt[d], 1);
  }
}

__global__ void dis_k(const int* __restrict__ cnt, float* __restrict__ dis, int n) {
  int i = blockIdx.x * 256 + threadIdx.x;
  if (i < n) dis[i] = rsqrtf((float)cnt[i] + 1.0f);
}

__global__ void scan_a_k(const int* __restrict__ cnt, int* __restrict__ excl,
                         int* __restrict__ bsum, int n) {
  __shared__ int sh[1024];
  int t = threadIdx.x;
  int gid = blockIdx.x * 1024 + t;
  int v = (gid < n) ? cnt[gid] : 0;
  sh[t] = v;
  __syncthreads();
  for (int off = 1; off < 1024; off <<= 1) {
    int x = (t >= off) ? sh[t - off] : 0;
    __syncthreads();
    sh[t] += x;
    __syncthreads();
  }
  if (gid < n) excl[gid] = sh[t] - v;
  if (t == 1023) bsum[blockIdx.x] = sh[1023];
}

__global__ void scan_b_k(int* __restrict__ bsum, int nb) {
  __shared__ int sh[1024];
  int t = threadIdx.x;
  int v = (t < nb) ? bsum[t] : 0;
  sh[t] = v;
  __syncthreads();
  for (int off = 1; off < 1024; off <<= 1) {
    int x = (t >= off) ? sh[t - off] : 0;
    __syncthreads();
    sh[t] += x;
    __syncthreads();
  }
  if (t < nb) bsum[t] = sh[t] - v;
}

__global__ void scan_c_k(int* __restrict__ row_ptr, const int* __restrict__ bsum,
                         const int* __restrict__ cnt, int* __restrict__ cursor, int n) {
  int gid = blockIdx.x * 1024 + threadIdx.x;
  if (gid < n) {
    int r = row_ptr[gid] + bsum[blockIdx.x];
    row_ptr[gid] = r;
    cursor[gid] = r;
    if (gid == n - 1) row_ptr[n] = r + cnt[gid];
  }
}

// legacy single-pass scatter (fallback for N > 2^17)
__global__ void fill_k(const int* __restrict__ src, const int* __restrict__ dst,
                       int* __restrict__ cursor, int* __restrict__ col, int e, int n) {
  int i = blockIdx.x * 256 + threadIdx.x;
  if (i < e) {
    int d = dst[i];
    if (d >= 0 && d < n) {
      int slot = atomicAdd(&cursor[d], 1);
      int s = src[i];
      s = min(max(s, 0), n - 1);
      col[slot] = s;
    }
  }
}

// ---- bucketed CSR fill: bucket = dst>>8 (256 rows); row_ptr gives bucket bases ----

__global__ void bcinit_k(const int* __restrict__ row_ptr, int* __restrict__ bcur,
                         int n, int nbuck) {
  int b = blockIdx.x * 256 + threadIdx.x;
  if (b < nbuck) {
    int r = b * RPB;
    if (r > n) r = n;
    bcur[b] = row_ptr[r];
  }
}

// pass A: bin edges into per-bucket contiguous regions; payload packs (dst&255, src)
__global__ __launch_bounds__(1024) void bin_k(
    const int* __restrict__ src, const int* __restrict__ dst,
    int* __restrict__ bcur, unsigned int* __restrict__ binned,
    int e, int n, int nbuck, int cpb) {
  __shared__ int hist[512];
  __shared__ int base_[512];
  __shared__ int cnt2[512];
  int t = threadIdx.x;
  int start = blockIdx.x * cpb;
  int endc = min(e, start + cpb);
  for (int b = t; b < nbuck; b += 1024) { hist[b] = 0; cnt2[b] = 0; }
  __syncthreads();
  for (int i = start + t; i < endc; i += 1024) {
    int d = dst[i];
    if (d >= 0 && d < n) atomicAdd(&hist[d >> 8], 1);
  }
  __syncthreads();
  for (int b = t; b < nbuck; b += 1024) {
    int h = hist[b];
    base_[b] = h ? atomicAdd(&bcur[b], h) : 0;
  }
  __syncthreads();
  for (int i = start + t; i < endc; i += 1024) {
    int d = dst[i];
    if (d >= 0 && d < n) {
      int bk = d >> 8;
      int s = src[i];
      s = min(max(s, 0), n - 1);
      int pos = base_[bk] + atomicAdd(&cnt2[bk], 1);
      binned[pos] = (((unsigned int)(d & 255)) << 17) | (unsigned int)s;
    }
  }
}

// pass B: per-bucket scatter with LDS row cursors; col writes stay in a 32KB window
__global__ __launch_bounds__(256) void scat_k(
    const unsigned int* __restrict__ binned, const int* __restrict__ row_ptr,
    int* __restrict__ col, int n) {
  __shared__ int cur[RPB];
  int b = blockIdx.x;
  int r0 = b * RPB;
  int r1 = min(n, r0 + RPB);
  int t = threadIdx.x;
  if (r0 + t < r1) cur[t] = row_ptr[r0 + t];
  __syncthreads();
  int e0 = row_ptr[r0];
  int e1 = row_ptr[r1];
  for (int i = e0 + t; i < e1; i += 256) {
    unsigned int p = binned[i];
    int dlow = (int)(p >> 17);
    int slot = atomicAdd(&cur[dlow], 1);
    col[slot] = (int)(p & 0x1FFFF);
  }
}

// ---------------- weight precomputation (linear collapse) ----------------
// Wc = W2 @ Wlin; Wfull = W1 @ Wc; b1c = b1 @ Wc; r2 = b2 @ Wlin + blin

__global__ __launch_bounds__(64) void wc_k(const float* __restrict__ W2,
                                           const float* __restrict__ Wlin,
                                           float* __restrict__ Wc) {
  __shared__ float row[FDIM];
  int k = blockIdx.x, t = threadIdx.x;
  for (int j = t; j < FDIM; j += 64) row[j] = W2[(size_t)k * FDIM + j];
  __syncthreads();
  if (t < FOUT) {
    float acc = 0.f;
    for (int j = 0; j < FDIM; ++j) acc += row[j] * Wlin[(size_t)j * FOUT + t];
    Wc[(size_t)k * FOUT + t] = acc;
  }
}

__global__ __launch_bounds__(64) void wfull_k(const float* __restrict__ W1,
                                              const float* __restrict__ Wc,
                                              float* __restrict__ Wfull) {
  __shared__ float row[FDIM];
  int k = blockIdx.x, t = threadIdx.x;
  for (int j = t; j < FDIM; j += 64) row[j] = W1[(size_t)k * FDIM + j];
  __syncthreads();
  if (t < FOUT) {
    float acc = 0.f;
    for (int j = 0; j < FDIM; ++j) acc += row[j] * Wc[(size_t)j * FOUT + t];
    Wfull[(size_t)k * FOUT + t] = acc;
  }
}

__global__ __launch_bounds__(64) void rvec_k(const float* __restrict__ b1,
                                             const float* __restrict__ Wc,
                                             const float* __restrict__ b2,
                                             const float* __restrict__ Wlin,
                                             const float* __restrict__ blin,
                                             float* __restrict__ b1c,
                                             float* __restrict__ r2) {
  int t = threadIdx.x;
  if (t < FOUT) {
    float a = 0.f, b = blin[t];
    for (int j = 0; j < FDIM; ++j) {
      a += b1[j] * Wc[(size_t)j * FOUT + t];
      b += b2[j] * Wlin[(size_t)j * FOUT + t];
    }
    b1c[t] = a;
    r2[t] = b;
  }
}

// WfT: bf16 B^T for MFMA, 48 rows (40 real + 8 zero-pad) x 256
__global__ void wft_k(const float* __restrict__ Wfull, unsigned short* __restrict__ WfT) {
  int o = blockIdx.x, k = threadIdx.x;
  WfT[(size_t)o * FDIM + k] = (o < FOUT) ? f2bf(Wfull[(size_t)k * FOUT + o]) : (unsigned short)0;
}

// ---------------- proj: Ys[N][40] = (X @ Wfull) * dis_row  (MFMA, bf16 inputs) ----------------

__global__ __launch_bounds__(256) void proj_k(
    const float* __restrict__ X, const unsigned short* __restrict__ WfT,
    const float* __restrict__ dis, float* __restrict__ Ys, int M) {
  __shared__ __align__(16) unsigned short Asm[64 * 40];   // 64 rows x 32 k, stride 40
  __shared__ __align__(16) unsigned short Bsm[48 * 264];  // 48 rows x 256 k, stride 264
  int t = threadIdx.x;
  int block_m = blockIdx.x * 64;
  int lane = t & 63, wave = t >> 6;
  int q = lane >> 4, rcol = lane & 15;
  for (int idx = t; idx < 48 * 256; idx += 256) {
    int o = idx >> 8, k = idx & 255;
    Bsm[o * 264 + k] = WfT[(size_t)o * FDIM + k];
  }
  floatx4 acc[3] = {};
  int arow = t >> 2, cc = (t & 3) * 8;
  int gm = block_m + arow;
  for (int kk = 0; kk < FDIM; kk += 32) {
    __syncthreads();  // also protects Bsm staging on first iteration
    {
      float4 v0 = {0, 0, 0, 0}, v1 = {0, 0, 0, 0};
      if (gm < M) {
        v0 = *(const float4*)(X + (size_t)gm * FDIM + kk + cc);
        v1 = *(const float4*)(X + (size_t)gm * FDIM + kk + cc + 4);
      }
      short8 pk;
      pk[0] = (short)f2bf(v0.x); pk[1] = (short)f2bf(v0.y);
      pk[2] = (short)f2bf(v0.z); pk[3] = (short)f2bf(v0.w);
      pk[4] = (short)f2bf(v1.x); pk[5] = (short)f2bf(v1.y);
      pk[6] = (short)f2bf(v1.z); pk[7] = (short)f2bf(v1.w);
      *(short8*)(Asm + arow * 40 + cc) = pk;
    }
    __syncthreads();
    short8 af = *(const short8*)(Asm + (wave * 16 + rcol) * 40 + q * 8);
    short8 b0 = *(const short8*)(Bsm + (rcol)*264 + kk + q * 8);
    short8 b1f = *(const short8*)(Bsm + (16 + rcol) * 264 + kk + q * 8);
    short8 b2f = *(const short8*)(Bsm + (32 + rcol) * 264 + kk + q * 8);
    acc[0] = __builtin_amdgcn_mfma_f32_16x16x32_bf16(af, b0, acc[0], 0, 0, 0);
    acc[1] = __builtin_amdgcn_mfma_f32_16x16x32_bf16(af, b1f, acc[1], 0, 0, 0);
    acc[2] = __builtin_amdgcn_mfma_f32_16x16x32_bf16(af, b2f, acc[2], 0, 0, 0);
  }
#pragma unroll
  for (int rr = 0; rr < 4; ++rr) {
    int m = block_m + wave * 16 + q * 4 + rr;
    if (m >= M) continue;
    float sc = dis[m];
    float* orow = Ys + (size_t)m * FOUT;
    orow[rcol] = acc[0][rr] * sc;
    orow[16 + rcol] = acc[1][rr] * sc;
    if (rcol < 8) orow[32 + rcol] = acc[2][rr] * sc;
  }
}

// ---------------- agg1: Z1s = (dis_i*(Ys_i + sum Ys_src) + b1c) * dis_i ----------------
// wave per dst row; lanes 0..39 hold features; 16-deep readlane/saddr gather batches

__global__ __launch_bounds__(256) void agg1_k(
    const float* __restrict__ T, const int* __restrict__ row_ptr,
    const int* __restrict__ col, const float* __restrict__ dis,
    const float* __restrict__ b1c, float* __restrict__ O, int n) {
  int wave = threadIdx.x >> 6, lane = threadIdx.x & 63;
  int wid = blockIdx.x * 4 + wave;
  int nw = gridDim.x * 4;
  bool act = lane < FOUT;
  float bv = act ? b1c[lane] : 0.f;
  for (int i = wid; i < n; i += nw) {
    float a = act ? T[(size_t)i * FOUT + lane] : 0.f;
    int beg = row_ptr[i], end = row_ptr[i + 1];
    for (int j0 = beg; j0 < end; j0 += 64) {
      int jj = j0 + lane;
      int cs = (jj < end) ? col[jj] : 0;
      int cc = min(64, end - j0);
      for (int k = 0; k < cc; k += 16) {
        int sl[16];
        float w[16];
#pragma unroll
        for (int u = 0; u < 16; ++u) {
          int ku = k + u;
          sl[u] = __builtin_amdgcn_readlane(cs, ku & 63);
          w[u] = (ku < cc) ? 1.f : 0.f;
        }
        float g[16];
#pragma unroll
        for (int u = 0; u < 16; ++u)
          g[u] = act ? T[(size_t)sl[u] * FOUT + lane] : 0.f;
#pragma unroll
        for (int u = 0; u < 16; ++u) a = fmaf(w[u], g[u], a);
      }
    }
    if (act) {
      float di = dis[i];
      O[(size_t)i * FOUT + lane] = (di * a + bv) * di;
    }
  }
}

// ---------------- agg2 + log_softmax: out = logsm( dis_i*(Z1s_i + sum Z1s_src) + r2 ) ----------------

__global__ __launch_bounds__(256) void agg2_k(
    const float* __restrict__ T, const int* __restrict__ row_ptr,
    const int* __restrict__ col, const float* __restrict__ dis,
    const float* __restrict__ r2, float* __restrict__ out, int n) {
  int wave = threadIdx.x >> 6, lane = threadIdx.x & 63;
  int wid = blockIdx.x * 4 + wave;
  int nw = gridDim.x * 4;
  bool act = lane < FOUT;
  float rv = act ? r2[lane] : 0.f;
  for (int i = wid; i < n; i += nw) {
    float a = act ? T[(size_t)i * FOUT + lane] : 0.f;
    int beg = row_ptr[i], end = row_ptr[i + 1];
    for (int j0 = beg; j0 < end; j0 += 64) {
      int jj = j0 + lane;
      int cs = (jj < end) ? col[jj] : 0;
      int cc = min(64, end - j0);
      for (int k = 0; k < cc; k += 16) {
        int sl[16];
        float w[16];
#pragma unroll
        for (int u = 0; u < 16; ++u) {
          int ku = k + u;
          sl[u] = __builtin_amdgcn_readlane(cs, ku & 63);
          w[u] = (ku < cc) ? 1.f : 0.f;
        }
        float g[16];
#pragma unroll
        for (int u = 0; u < 16; ++u)
          g[u] = act ? T[(size_t)sl[u] * FOUT + lane] : 0.f;
#pragma unroll
        for (int u = 0; u < 16; ++u) a = fmaf(w[u], g[u], a);
      }
    }
    float di = dis[i];
    float v = act ? (di * a + rv) : -3.4e38f;
    float m = v;
#pragma unroll
    for (int off = 32; off; off >>= 1) m = fmaxf(m, __shfl_xor(m, off));
    float e = act ? __expf(v - m) : 0.f;
    float s = e;
#pragma unroll
    for (int off = 32; off; off >>= 1) s += __shfl_xor(s, off);
    float lg = m + __logf(s);
    if (act) out[(size_t)i * FOUT + lane] = v - lg;
  }
}

// ---------------- launch ----------------

extern "C" void kernel_launch(void* const* d_in, const int* in_sizes, int n_in,
                              void* d_out, int out_size, void* d_ws, size_t ws_size,
                              hipStream_t stream) {
  const float* x   = (const float*)d_in[0];
  const int* eraw  = (const int*)d_in[1];
  const float* W1  = (const float*)d_in[2];
  const float* b1  = (const float*)d_in[3];
  const float* W2  = (const float*)d_in[4];
  const float* b2  = (const float*)d_in[5];
  const float* Wl  = (const float*)d_in[6];
  const float* bl  = (const float*)d_in[7];
  float* out = (float*)d_out;

  const int N = in_sizes[0] / FDIM;
  const int E = in_sizes[1] / 2;

  char* w = (char*)d_ws;
  size_t off = 0;
  auto take = [&](size_t bytes) {
    void* p = w + off;
    off = (off + bytes + 255) & ~(size_t)255;
    return p;
  };
  int* cnt     = (int*)take((size_t)N * 4);
  int* cursor  = (int*)take((size_t)N * 4);   // doubles as per-bucket cursor
  int* row_ptr = (int*)take((size_t)(N + 1) * 4);
  float* dis   = (float*)take((size_t)N * 4);
  int* bsum    = (int*)take(4096);
  int* eflag   = (int*)take(256);
  float* Wc    = (float*)take((size_t)FDIM * FOUT * 4);
  float* Wfull = (float*)take((size_t)FDIM * FOUT * 4);
  unsigned short* WfT = (unsigned short*)take((size_t)48 * FDIM * 2);
  float* b1c   = (float*)take(256);
  float* r2    = (float*)take(256);
  int* colx    = (int*)take((size_t)E * 4);

  size_t pairBytes = (size_t)2 * E * 4;
  size_t tabBytes  = (size_t)N * FOUT * 4;
  // regionA hosts srcN/dstN early, then Ys (both dead/live windows disjoint)
  size_t rABytes = pairBytes > tabBytes ? pairBytes : tabBytes;
  char* regionA = (char*)take(rABytes);
  int* srcN = (int*)regionA;
  int* dstN = srcN + E;
  float* Ys = (float*)regionA;
  // regionB hosts binned early, then Z1s
  size_t binBytes = (size_t)E * 4;
  size_t rBBytes = binBytes > tabBytes ? binBytes : tabBytes;
  char* regionB = (char*)take(rBBytes);
  unsigned int* binned = (unsigned int*)regionB;
  float* Z1s = (float*)regionB;
  (void)n_in; (void)out_size; (void)ws_size;

  int gE = (E + 255) / 256;
  int gN = (N + 255) / 256;
  int NB = (N + 1023) / 1024;
  int gP = (N + 63) / 64;
  int nbuck = (N + RPB - 1) / RPB;
  bool bucketed = (N <= (1 << 17));  // 17-bit src pack + 512-entry LDS hists

  int probe_words = 65536 < 2 * E ? 65536 : 2 * E;
  hipLaunchKernelGGL(detect_k, dim3(1), dim3(256), 0, stream, eraw, probe_words, eflag);
  hipLaunchKernelGGL(normalize_k, dim3(gE), dim3(256), 0, stream, eraw, eflag, srcN, dstN, E);

  hipLaunchKernelGGL(zero_cnt_k, dim3(gN), dim3(256), 0, stream, cnt, N);
  hipLaunchKernelGGL(count_k, dim3(gE), dim3(256), 0, stream, dstN, cnt, E, N);
  hipLaunchKernelGGL(dis_k, dim3(gN), dim3(256), 0, stream, cnt, dis, N);
  hipLaunchKernelGGL(scan_a_k, dim3(NB), dim3(1024), 0, stream, cnt, row_ptr, bsum, N);
  hipLaunchKernelGGL(scan_b_k, dim3(1), dim3(1024), 0, stream, bsum, NB);
  hipLaunchKernelGGL(scan_c_k, dim3(NB), dim3(1024), 0, stream, row_ptr, bsum, cnt, cursor, N);
  if (bucketed) {
    int nblk = 256;
    int cpb = (E + nblk - 1) / nblk;
    hipLaunchKernelGGL(bcinit_k, dim3((nbuck + 255) / 256), dim3(256), 0, stream,
                       row_ptr, cursor, N, nbuck);
    hipLaunchKernelGGL(bin_k, dim3(nblk), dim3(1024), 0, stream,
                       srcN, dstN, cursor, binned, E, N, nbuck, cpb);
    hipLaunchKernelGGL(scat_k, dim3(nbuck), dim3(256), 0, stream,
                       binned, row_ptr, colx, N);
  } else {
    hipLaunchKernelGGL(fill_k, dim3(gE), dim3(256), 0, stream, srcN, dstN, cursor, colx, E, N);
  }

  // collapsed weights
  hipLaunchKernelGGL(wc_k, dim3(FDIM), dim3(64), 0, stream, W2, Wl, Wc);
  hipLaunchKernelGGL(wfull_k, dim3(FDIM), dim3(64), 0, stream, W1, Wc, Wfull);
  hipLaunchKernelGGL(rvec_k, dim3(1), dim3(64), 0, stream, b1, Wc, b2, Wl, bl, b1c, r2);
  hipLaunchKernelGGL(wft_k, dim3(48), dim3(FDIM), 0, stream, Wfull, WfT);

  // Ys = (X @ Wfull) * dis_row   (overwrites srcN/dstN, dead after bin/fill)
  hipLaunchKernelGGL(proj_k, dim3(gP), dim3(256), 0, stream, x, WfT, dis, Ys, N);
  // Z1s = (dis_i*(Ys_i + sum) + b1c) * dis_i   (overwrites binned, dead after scat)
  hipLaunchKernelGGL(agg1_k, dim3(2048), dim3(256), 0, stream,
                     Ys, row_ptr, colx, dis, b1c, Z1s, N);
  // out = logsm( dis_i*(Z1s_i + sum) + r2 )
  hipLaunchKernelGGL(agg2_k, dim3(2048), dim3(256), 0, stream,
                     Z1s, row_ptr, colx, dis, r2, out, N);
}

// Round 4
// 514.863 us; speedup vs baseline: 2.2838x; 1.1895x over previous
//
#include <hip/hip_runtime.h>
#include <hip/hip_bf16.h>

#define FDIM 256
#define FOUT 40
#define RPB 256   // rows per bucket in CSR-build binning

typedef __attribute__((ext_vector_type(8))) short short8;
typedef __attribute__((ext_vector_type(4))) float floatx4;

__device__ __forceinline__ float bf2f(unsigned short u) {
  unsigned int x = ((unsigned int)u) << 16;
  float f;
  __builtin_memcpy(&f, &x, 4);
  return f;
}
__device__ __forceinline__ unsigned short f2bf(float f) {
  __hip_bfloat16 h = __float2bfloat16(f);
  unsigned short u;
  __builtin_memcpy(&u, &h, 2);
  return u;
}

// ---------------- edge_index layout detection ----------------

__global__ void detect_k(const int* __restrict__ raw, int nwords, int* __restrict__ flag) {
  if (threadIdx.x == 0) *flag = 0;
  __syncthreads();
  int found = 0;
  for (int w = 1 + 2 * threadIdx.x; w < nwords; w += 512)
    if (raw[w] != 0) { found = 1; break; }
  if (found) atomicOr(flag, 1);  // 1 => int32 layout
}

// legacy normalization (fallback path only)
__global__ void normalize_k(const int* __restrict__ raw, const int* __restrict__ flag,
                            int* __restrict__ srcN, int* __restrict__ dstN, int e) {
  int i = blockIdx.x * 256 + threadIdx.x;
  if (i >= e) return;
  if (*flag) {
    srcN[i] = raw[i];
    dstN[i] = raw[e + i];
  } else {
    srcN[i] = raw[2 * i];
    dstN[i] = raw[2 * (e + i)];
  }
}

// ---------------- legacy CSR build (fallback for N > 2^17) ----------------

__global__ void zero_cnt_k(int* cnt, int n) {
  int i = blockIdx.x * 256 + threadIdx.x;
  if (i < n) cnt[i] = 0;
}

__global__ void count_k(const int* __restrict__ dst, int* __restrict__ cnt, int e, int n) {
  int i = blockIdx.x * 256 + threadIdx.x;
  if (i < e) {
    int d = dst[i];
    if (d >= 0 && d < n) atomicAdd(&cnt[d], 1);
  }
}

__global__ void dis_leg_k(const int* __restrict__ cnt, float* __restrict__ dis, int n) {
  int i = blockIdx.x * 256 + threadIdx.x;
  if (i < n) dis[i] = rsqrtf((float)cnt[i] + 1.0f);
}

__global__ void scan_a_k(const int* __restrict__ cnt, int* __restrict__ excl,
                         int* __restrict__ bsum, int n) {
  __shared__ int sh[1024];
  int t = threadIdx.x;
  int gid = blockIdx.x * 1024 + t;
  int v = (gid < n) ? cnt[gid] : 0;
  sh[t] = v;
  __syncthreads();
  for (int off = 1; off < 1024; off <<= 1) {
    int x = (t >= off) ? sh[t - off] : 0;
    __syncthreads();
    sh[t] += x;
    __syncthreads();
  }
  if (gid < n) excl[gid] = sh[t] - v;
  if (t == 1023) bsum[blockIdx.x] = sh[1023];
}

__global__ void scan_b_k(int* __restrict__ bsum, int nb) {
  __shared__ int sh[1024];
  int t = threadIdx.x;
  int v = (t < nb) ? bsum[t] : 0;
  sh[t] = v;
  __syncthreads();
  for (int off = 1; off < 1024; off <<= 1) {
    int x = (t >= off) ? sh[t - off] : 0;
    __syncthreads();
    sh[t] += x;
    __syncthreads();
  }
  if (t < nb) bsum[t] = sh[t] - v;
}

__global__ void scan_c_k(int* __restrict__ row_ptr, const int* __restrict__ bsum,
                         const int* __restrict__ cnt, int* __restrict__ cursor, int n) {
  int gid = blockIdx.x * 1024 + threadIdx.x;
  if (gid < n) {
    int r = row_ptr[gid] + bsum[blockIdx.x];
    row_ptr[gid] = r;
    cursor[gid] = r;
    if (gid == n - 1) row_ptr[n] = r + cnt[gid];
  }
}

__global__ void fill_k(const int* __restrict__ src, const int* __restrict__ dst,
                       int* __restrict__ cursor, int* __restrict__ col, int e, int n) {
  int i = blockIdx.x * 256 + threadIdx.x;
  if (i < e) {
    int d = dst[i];
    if (d >= 0 && d < n) {
      int slot = atomicAdd(&cursor[d], 1);
      int s = src[i];
      s = min(max(s, 0), n - 1);
      col[slot] = s;
    }
  }
}

// ---------------- bucket-first CSR build (no global per-row atomics) ----------------
// bucket = dst >> 8 (256 rows, <= 512 buckets for N <= 2^17)

__global__ __launch_bounds__(512) void zerob_k(int* __restrict__ bcnt, int nbuck) {
  int t = threadIdx.x;
  if (t < nbuck) bcnt[t] = 0;
}

// pass 0: bucket histogram straight from raw edges; <=512 global atomics per block
__global__ __launch_bounds__(256) void bhist_k(
    const int* __restrict__ raw, const int* __restrict__ flag,
    int* __restrict__ bcnt, int e, int n, int nbuck, int cpb) {
  __shared__ int hist[512];
  int t = threadIdx.x;
  for (int b = t; b < nbuck; b += 256) hist[b] = 0;
  __syncthreads();
  int fl = *flag;
  int start = blockIdx.x * cpb;
  int endc = min(e, start + cpb);
  for (int i = start + t; i < endc; i += 256) {
    int d = fl ? raw[e + i] : raw[2 * (e + i)];
    if (d >= 0 && d < n) atomicAdd(&hist[d >> 8], 1);
  }
  __syncthreads();
  for (int b = t; b < nbuck; b += 256)
    if (hist[b]) atomicAdd(&bcnt[b], hist[b]);
}

// pass 1: scan bucket counts -> bases + cursors (single block)
__global__ __launch_bounds__(512) void bscan_k(
    const int* __restrict__ bcnt, int* __restrict__ bbase,
    int* __restrict__ bcur, int nbuck) {
  __shared__ int sh[512];
  int t = threadIdx.x;
  int v = (t < nbuck) ? bcnt[t] : 0;
  sh[t] = v;
  __syncthreads();
  for (int off = 1; off < 512; off <<= 1) {
    int x = (t >= off) ? sh[t - off] : 0;
    __syncthreads();
    sh[t] += x;
    __syncthreads();
  }
  if (t < nbuck) {
    int ex = sh[t] - v;
    bbase[t] = ex;
    bcur[t] = ex;
  }
  if (t == nbuck - 1) bbase[nbuck] = sh[t];
}

// pass 2: bin edges (from raw) into per-bucket contiguous regions; payload (dst&255, src)
__global__ __launch_bounds__(1024) void bin2_k(
    const int* __restrict__ raw, const int* __restrict__ flag,
    int* __restrict__ bcur, unsigned int* __restrict__ binned,
    int e, int n, int nbuck, int cpb) {
  __shared__ int hist[512];
  __shared__ int base_[512];
  __shared__ int cnt2[512];
  int t = threadIdx.x;
  int fl = *flag;
  int start = blockIdx.x * cpb;
  int endc = min(e, start + cpb);
  for (int b = t; b < nbuck; b += 1024) { hist[b] = 0; cnt2[b] = 0; }
  __syncthreads();
  for (int i = start + t; i < endc; i += 1024) {
    int d = fl ? raw[e + i] : raw[2 * (e + i)];
    if (d >= 0 && d < n) atomicAdd(&hist[d >> 8], 1);
  }
  __syncthreads();
  for (int b = t; b < nbuck; b += 1024) {
    int h = hist[b];
    base_[b] = h ? atomicAdd(&bcur[b], h) : 0;
  }
  __syncthreads();
  for (int i = start + t; i < endc; i += 1024) {
    int d = fl ? raw[e + i] : raw[2 * (e + i)];
    if (d >= 0 && d < n) {
      int s = fl ? raw[i] : raw[2 * i];
      s = min(max(s, 0), n - 1);
      int bk = d >> 8;
      int pos = base_[bk] + atomicAdd(&cnt2[bk], 1);
      binned[pos] = (((unsigned int)(d & 255)) << 17) | (unsigned int)s;
    }
  }
}

// pass 3: per-bucket row count + dis + row_ptr (LDS scan) + scatter to col
__global__ __launch_bounds__(256) void scatcnt_k(
    const unsigned int* __restrict__ binned, const int* __restrict__ bbase,
    int* __restrict__ row_ptr, float* __restrict__ dis,
    int* __restrict__ col, int n) {
  __shared__ int cnt[RPB];
  __shared__ int sc[RPB];
  __shared__ int cur[RPB];
  int b = blockIdx.x;
  int r0 = b * RPB;
  int r1 = min(n, r0 + RPB);
  int nr = r1 - r0;
  int t = threadIdx.x;
  cnt[t] = 0;
  __syncthreads();
  int e0 = bbase[b], e1 = bbase[b + 1];
  for (int i = e0 + t; i < e1; i += 256)
    atomicAdd(&cnt[binned[i] >> 17], 1);
  __syncthreads();
  int v = cnt[t];
  if (t < nr) dis[r0 + t] = rsqrtf((float)v + 1.0f);
  sc[t] = v;
  __syncthreads();
  for (int off = 1; off < 256; off <<= 1) {
    int x = (t >= off) ? sc[t - off] : 0;
    __syncthreads();
    sc[t] += x;
    __syncthreads();
  }
  int base = e0 + sc[t] - v;  // exclusive
  cur[t] = base;
  if (t < nr) row_ptr[r0 + t] = base;
  if (t == 0 && r1 == n) row_ptr[n] = e1;
  __syncthreads();
  for (int i = e0 + t; i < e1; i += 256) {
    unsigned int p = binned[i];
    int dlow = (int)(p >> 17);
    int slot = atomicAdd(&cur[dlow], 1);
    col[slot] = (int)(p & 0x1FFFF);
  }
}

// ---------------- weight precomputation (linear collapse) ----------------
// Wc = W2 @ Wlin; Wfull = W1 @ Wc; b1c = b1 @ Wc; r2 = b2 @ Wlin + blin

__global__ __launch_bounds__(64) void wc_k(const float* __restrict__ W2,
                                           const float* __restrict__ Wlin,
                                           float* __restrict__ Wc) {
  __shared__ float row[FDIM];
  int k = blockIdx.x, t = threadIdx.x;
  for (int j = t; j < FDIM; j += 64) row[j] = W2[(size_t)k * FDIM + j];
  __syncthreads();
  if (t < FOUT) {
    float acc = 0.f;
    for (int j = 0; j < FDIM; ++j) acc += row[j] * Wlin[(size_t)j * FOUT + t];
    Wc[(size_t)k * FOUT + t] = acc;
  }
}

__global__ __launch_bounds__(64) void wfull_k(const float* __restrict__ W1,
                                              const float* __restrict__ Wc,
                                              float* __restrict__ Wfull) {
  __shared__ float row[FDIM];
  int k = blockIdx.x, t = threadIdx.x;
  for (int j = t; j < FDIM; j += 64) row[j] = W1[(size_t)k * FDIM + j];
  __syncthreads();
  if (t < FOUT) {
    float acc = 0.f;
    for (int j = 0; j < FDIM; ++j) acc += row[j] * Wc[(size_t)j * FOUT + t];
    Wfull[(size_t)k * FOUT + t] = acc;
  }
}

__global__ __launch_bounds__(64) void rvec_k(const float* __restrict__ b1,
                                             const float* __restrict__ Wc,
                                             const float* __restrict__ b2,
                                             const float* __restrict__ Wlin,
                                             const float* __restrict__ blin,
                                             float* __restrict__ b1c,
                                             float* __restrict__ r2) {
  int t = threadIdx.x;
  if (t < FOUT) {
    float a = 0.f, b = blin[t];
    for (int j = 0; j < FDIM; ++j) {
      a += b1[j] * Wc[(size_t)j * FOUT + t];
      b += b2[j] * Wlin[(size_t)j * FOUT + t];
    }
    b1c[t] = a;
    r2[t] = b;
  }
}

// WfT: bf16 B^T for MFMA, 48 rows (40 real + 8 zero-pad) x 256
__global__ void wft_k(const float* __restrict__ Wfull, unsigned short* __restrict__ WfT) {
  int o = blockIdx.x, k = threadIdx.x;
  WfT[(size_t)o * FDIM + k] = (o < FOUT) ? f2bf(Wfull[(size_t)k * FOUT + o]) : (unsigned short)0;
}

// ---------------- proj: Ys[N][40] = (X @ Wfull) * dis_row  (MFMA, bf16 inputs) ----------------

__global__ __launch_bounds__(256) void proj_k(
    const float* __restrict__ X, const unsigned short* __restrict__ WfT,
    const float* __restrict__ dis, float* __restrict__ Ys, int M) {
  __shared__ __align__(16) unsigned short Asm[64 * 40];   // 64 rows x 32 k, stride 40
  __shared__ __align__(16) unsigned short Bsm[48 * 264];  // 48 rows x 256 k, stride 264
  int t = threadIdx.x;
  int block_m = blockIdx.x * 64;
  int lane = t & 63, wave = t >> 6;
  int q = lane >> 4, rcol = lane & 15;
  for (int idx = t; idx < 48 * 256; idx += 256) {
    int o = idx >> 8, k = idx & 255;
    Bsm[o * 264 + k] = WfT[(size_t)o * FDIM + k];
  }
  floatx4 acc[3] = {};
  int arow = t >> 2, cc = (t & 3) * 8;
  int gm = block_m + arow;
  for (int kk = 0; kk < FDIM; kk += 32) {
    __syncthreads();  // also protects Bsm staging on first iteration
    {
      float4 v0 = {0, 0, 0, 0}, v1 = {0, 0, 0, 0};
      if (gm < M) {
        v0 = *(const float4*)(X + (size_t)gm * FDIM + kk + cc);
        v1 = *(const float4*)(X + (size_t)gm * FDIM + kk + cc + 4);
      }
      short8 pk;
      pk[0] = (short)f2bf(v0.x); pk[1] = (short)f2bf(v0.y);
      pk[2] = (short)f2bf(v0.z); pk[3] = (short)f2bf(v0.w);
      pk[4] = (short)f2bf(v1.x); pk[5] = (short)f2bf(v1.y);
      pk[6] = (short)f2bf(v1.z); pk[7] = (short)f2bf(v1.w);
      *(short8*)(Asm + arow * 40 + cc) = pk;
    }
    __syncthreads();
    short8 af = *(const short8*)(Asm + (wave * 16 + rcol) * 40 + q * 8);
    short8 b0 = *(const short8*)(Bsm + (rcol)*264 + kk + q * 8);
    short8 b1f = *(const short8*)(Bsm + (16 + rcol) * 264 + kk + q * 8);
    short8 b2f = *(const short8*)(Bsm + (32 + rcol) * 264 + kk + q * 8);
    acc[0] = __builtin_amdgcn_mfma_f32_16x16x32_bf16(af, b0, acc[0], 0, 0, 0);
    acc[1] = __builtin_amdgcn_mfma_f32_16x16x32_bf16(af, b1f, acc[1], 0, 0, 0);
    acc[2] = __builtin_amdgcn_mfma_f32_16x16x32_bf16(af, b2f, acc[2], 0, 0, 0);
  }
#pragma unroll
  for (int rr = 0; rr < 4; ++rr) {
    int m = block_m + wave * 16 + q * 4 + rr;
    if (m >= M) continue;
    float sc = dis[m];
    float* orow = Ys + (size_t)m * FOUT;
    orow[rcol] = acc[0][rr] * sc;
    orow[16 + rcol] = acc[1][rr] * sc;
    if (rcol < 8) orow[32 + rcol] = acc[2][rr] * sc;
  }
}

// ---------------- agg1: Z1s = (dis_i*(Ys_i + sum Ys_src) + b1c) * dis_i ----------------
// wave per dst row; lanes 0..39 hold features; 16-deep readlane/saddr gather batches

__global__ __launch_bounds__(256) void agg1_k(
    const float* __restrict__ T, const int* __restrict__ row_ptr,
    const int* __restrict__ col, const float* __restrict__ dis,
    const float* __restrict__ b1c, float* __restrict__ O, int n) {
  int wave = threadIdx.x >> 6, lane = threadIdx.x & 63;
  int wid = blockIdx.x * 4 + wave;
  int nw = gridDim.x * 4;
  bool act = lane < FOUT;
  float bv = act ? b1c[lane] : 0.f;
  for (int i = wid; i < n; i += nw) {
    float a = act ? T[(size_t)i * FOUT + lane] : 0.f;
    int beg = row_ptr[i], end = row_ptr[i + 1];
    for (int j0 = beg; j0 < end; j0 += 64) {
      int jj = j0 + lane;
      int cs = (jj < end) ? col[jj] : 0;
      int cc = min(64, end - j0);
      for (int k = 0; k < cc; k += 16) {
        int sl[16];
        float w[16];
#pragma unroll
        for (int u = 0; u < 16; ++u) {
          int ku = k + u;
          sl[u] = __builtin_amdgcn_readlane(cs, ku & 63);
          w[u] = (ku < cc) ? 1.f : 0.f;
        }
        float g[16];
#pragma unroll
        for (int u = 0; u < 16; ++u)
          g[u] = act ? T[(size_t)sl[u] * FOUT + lane] : 0.f;
#pragma unroll
        for (int u = 0; u < 16; ++u) a = fmaf(w[u], g[u], a);
      }
    }
    if (act) {
      float di = dis[i];
      O[(size_t)i * FOUT + lane] = (di * a + bv) * di;
    }
  }
}

// ---------------- agg2 + log_softmax: out = logsm( dis_i*(Z1s_i + sum Z1s_src) + r2 ) ----------------

__global__ __launch_bounds__(256) void agg2_k(
    const float* __restrict__ T, const int* __restrict__ row_ptr,
    const int* __restrict__ col, const float* __restrict__ dis,
    const float* __restrict__ r2, float* __restrict__ out, int n) {
  int wave = threadIdx.x >> 6, lane = threadIdx.x & 63;
  int wid = blockIdx.x * 4 + wave;
  int nw = gridDim.x * 4;
  bool act = lane < FOUT;
  float rv = act ? r2[lane] : 0.f;
  for (int i = wid; i < n; i += nw) {
    float a = act ? T[(size_t)i * FOUT + lane] : 0.f;
    int beg = row_ptr[i], end = row_ptr[i + 1];
    for (int j0 = beg; j0 < end; j0 += 64) {
      int jj = j0 + lane;
      int cs = (jj < end) ? col[jj] : 0;
      int cc = min(64, end - j0);
      for (int k = 0; k < cc; k += 16) {
        int sl[16];
        float w[16];
#pragma unroll
        for (int u = 0; u < 16; ++u) {
          int ku = k + u;
          sl[u] = __builtin_amdgcn_readlane(cs, ku & 63);
          w[u] = (ku < cc) ? 1.f : 0.f;
        }
        float g[16];
#pragma unroll
        for (int u = 0; u < 16; ++u)
          g[u] = act ? T[(size_t)sl[u] * FOUT + lane] : 0.f;
#pragma unroll
        for (int u = 0; u < 16; ++u) a = fmaf(w[u], g[u], a);
      }
    }
    float di = dis[i];
    float v = act ? (di * a + rv) : -3.4e38f;
    float m = v;
#pragma unroll
    for (int off = 32; off; off >>= 1) m = fmaxf(m, __shfl_xor(m, off));
    float e = act ? __expf(v - m) : 0.f;
    float s = e;
#pragma unroll
    for (int off = 32; off; off >>= 1) s += __shfl_xor(s, off);
    float lg = m + __logf(s);
    if (act) out[(size_t)i * FOUT + lane] = v - lg;
  }
}

// ---------------- launch ----------------

extern "C" void kernel_launch(void* const* d_in, const int* in_sizes, int n_in,
                              void* d_out, int out_size, void* d_ws, size_t ws_size,
                              hipStream_t stream) {
  const float* x   = (const float*)d_in[0];
  const int* eraw  = (const int*)d_in[1];
  const float* W1  = (const float*)d_in[2];
  const float* b1  = (const float*)d_in[3];
  const float* W2  = (const float*)d_in[4];
  const float* b2  = (const float*)d_in[5];
  const float* Wl  = (const float*)d_in[6];
  const float* bl  = (const float*)d_in[7];
  float* out = (float*)d_out;

  const int N = in_sizes[0] / FDIM;
  const int E = in_sizes[1] / 2;

  char* w = (char*)d_ws;
  size_t off = 0;
  auto take = [&](size_t bytes) {
    void* p = w + off;
    off = (off + bytes + 255) & ~(size_t)255;
    return p;
  };
  int* cnt     = (int*)take((size_t)N * 4);   // legacy path only
  int* cursor  = (int*)take((size_t)N * 4);   // legacy path only
  int* row_ptr = (int*)take((size_t)(N + 1) * 4);
  float* dis   = (float*)take((size_t)N * 4);
  int* bsum    = (int*)take(4096);
  int* eflag   = (int*)take(256);
  int* bcnt    = (int*)take(512 * 4);
  int* bbase   = (int*)take(513 * 4);
  int* bcur    = (int*)take(512 * 4);
  float* Wc    = (float*)take((size_t)FDIM * FOUT * 4);
  float* Wfull = (float*)take((size_t)FDIM * FOUT * 4);
  unsigned short* WfT = (unsigned short*)take((size_t)48 * FDIM * 2);
  float* b1c   = (float*)take(256);
  float* r2    = (float*)take(256);
  int* colx    = (int*)take((size_t)E * 4);

  size_t pairBytes = (size_t)2 * E * 4;
  size_t tabBytes  = (size_t)N * FOUT * 4;
  // regionA hosts srcN/dstN (legacy path only), then Ys
  size_t rABytes = pairBytes > tabBytes ? pairBytes : tabBytes;
  char* regionA = (char*)take(rABytes);
  int* srcN = (int*)regionA;
  int* dstN = srcN + E;
  float* Ys = (float*)regionA;
  // regionB hosts binned early, then Z1s
  size_t binBytes = (size_t)E * 4;
  size_t rBBytes = binBytes > tabBytes ? binBytes : tabBytes;
  char* regionB = (char*)take(rBBytes);
  unsigned int* binned = (unsigned int*)regionB;
  float* Z1s = (float*)regionB;
  (void)n_in; (void)out_size; (void)ws_size;

  int gE = (E + 255) / 256;
  int gN = (N + 255) / 256;
  int NB = (N + 1023) / 1024;
  int gP = (N + 63) / 64;
  int nbuck = (N + RPB - 1) / RPB;
  bool bucketed = (N <= (1 << 17));  // 17-bit src pack + 512-entry bucket arrays

  int probe_words = 65536 < 2 * E ? 65536 : 2 * E;
  hipLaunchKernelGGL(detect_k, dim3(1), dim3(256), 0, stream, eraw, probe_words, eflag);

  if (bucketed) {
    int nblk = 256;
    int cpb = (E + nblk - 1) / nblk;
    hipLaunchKernelGGL(zerob_k, dim3(1), dim3(512), 0, stream, bcnt, nbuck);
    hipLaunchKernelGGL(bhist_k, dim3(nblk), dim3(256), 0, stream,
                       eraw, eflag, bcnt, E, N, nbuck, cpb);
    hipLaunchKernelGGL(bscan_k, dim3(1), dim3(512), 0, stream, bcnt, bbase, bcur, nbuck);
    hipLaunchKernelGGL(bin2_k, dim3(nblk), dim3(1024), 0, stream,
                       eraw, eflag, bcur, binned, E, N, nbuck, cpb);
    hipLaunchKernelGGL(scatcnt_k, dim3(nbuck), dim3(256), 0, stream,
                       binned, bbase, row_ptr, dis, colx, N);
  } else {
    hipLaunchKernelGGL(normalize_k, dim3(gE), dim3(256), 0, stream, eraw, eflag, srcN, dstN, E);
    hipLaunchKernelGGL(zero_cnt_k, dim3(gN), dim3(256), 0, stream, cnt, N);
    hipLaunchKernelGGL(count_k, dim3(gE), dim3(256), 0, stream, dstN, cnt, E, N);
    hipLaunchKernelGGL(dis_leg_k, dim3(gN), dim3(256), 0, stream, cnt, dis, N);
    hipLaunchKernelGGL(scan_a_k, dim3(NB), dim3(1024), 0, stream, cnt, row_ptr, bsum, N);
    hipLaunchKernelGGL(scan_b_k, dim3(1), dim3(1024), 0, stream, bsum, NB);
    hipLaunchKernelGGL(scan_c_k, dim3(NB), dim3(1024), 0, stream, row_ptr, bsum, cnt, cursor, N);
    hipLaunchKernelGGL(fill_k, dim3(gE), dim3(256), 0, stream, srcN, dstN, cursor, colx, E, N);
  }

  // collapsed weights
  hipLaunchKernelGGL(wc_k, dim3(FDIM), dim3(64), 0, stream, W2, Wl, Wc);
  hipLaunchKernelGGL(wfull_k, dim3(FDIM), dim3(64), 0, stream, W1, Wc, Wfull);
  hipLaunchKernelGGL(rvec_k, dim3(1), dim3(64), 0, stream, b1, Wc, b2, Wl, bl, b1c, r2);
  hipLaunchKernelGGL(wft_k, dim3(48), dim3(FDIM), 0, stream, Wfull, WfT);

  // Ys = (X @ Wfull) * dis_row   (overwrites srcN/dstN region; dead in bucketed path)
  hipLaunchKernelGGL(proj_k, dim3(gP), dim3(256), 0, stream, x, WfT, dis, Ys, N);
  // Z1s = (dis_i*(Ys_i + sum) + b1c) * dis_i   (overwrites binned, dead after scatcnt)
  hipLaunchKernelGGL(agg1_k, dim3(2048), dim3(256), 0, stream,
                     Ys, row_ptr, colx, dis, b1c, Z1s, N);
  // out = logsm( dis_i*(Z1s_i + sum) + r2 )
  hipLaunchKernelGGL(agg2_k, dim3(2048), dim3(256), 0, stream,
                     Z1s, row_ptr, colx, dis, r2, out, N);
}